// Round 6
// baseline (708.567 us; speedup 1.0000x reference)
//
#include <hip/hip_runtime.h>
#include <hip/hip_bf16.h>

#define HH 160
#define WW 160
#define HW 25600
#define NC 256
#define NB 8

typedef short short8 __attribute__((ext_vector_type(8)));
typedef float f32x4 __attribute__((ext_vector_type(4)));

__device__ __forceinline__ unsigned short f2bf(float f) {
    unsigned u = __float_as_uint(f);
    u += 0x7fffu + ((u >> 16) & 1u);   // RNE
    return (unsigned short)(u >> 16);
}
__device__ __forceinline__ float bf2f(unsigned short h) {
    return __uint_as_float(((unsigned)h) << 16);
}

// ---------------- K0: fold BN into align 1x1 conv, split hi/lo bf16, pre-pack ----------------
// Writes the padded per-kk LDS image directly: wpkh[kk*10240 + co*40 + kq] (kq = k - 32*kk).
__global__ void k0_fold(const float* __restrict__ aw, const float* __restrict__ ag,
                        const float* __restrict__ ab, const float* __restrict__ am,
                        const float* __restrict__ av,
                        unsigned short* __restrict__ wpkh, unsigned short* __restrict__ wpkl,
                        float* __restrict__ biasp) {
    int co = blockIdx.x, t = threadIdx.x;       // t = k (ci)
    float sc = ag[co] * rsqrtf(av[co] + 1e-5f);
    float w = aw[co * 256 + t] * sc;
    unsigned short h = f2bf(w);
    int kk = t >> 5, kq = t & 31;
    wpkh[kk * 10240 + co * 40 + kq] = h;
    wpkl[kk * 10240 + co * 40 + kq] = f2bf(w - bf2f(h));
    if (t == 0) biasp[co] = ab[co] - am[co] * sc;
}

// ---------------- K0b: fold the 49-way mean of conv2 into effective weights ----------------
__global__ void k0b_fold2(const float* __restrict__ ow2, const float* __restrict__ ob2,
                          float* __restrict__ weff, float* __restrict__ beff) {
    int t = threadIdx.x;
    if (t < 288) {
        int g = t / 144, r = t - g * 144;
        float s = 0.f;
        for (int q = 0; q < 49; q++) s += ow2[(size_t)(g * 49 + q) * 144 + r];
        weff[t] = s * (1.f / 49.f);
    }
    if (t < 2) {
        float s = 0.f;
        for (int q = 0; q < 49; q++) s += ob2[t * 49 + q];
        beff[t] = s * (1.f / 49.f);
    }
}

// ---------------- K1: align GEMM (split-bf16 MFMA, ~fp32) + bias + SiLU ----------------
// 512 threads = 8 waves; BM=256 (wave owns 32 co), BN=128, BK=32.
// launch_bounds(512,4): VGPR<=128 so 2 blocks/CU = 4 waves/SIMD (occupancy was the R3 limiter).
// B staging: 1 pixel x 8 k per thread -> single aligned b128 hi/lo LDS writes.
// NOTE: nt loop MUST be fully unrolled (R1 post-mortem: runtime-indexed acc -> scratch).
__global__ __launch_bounds__(512, 4) void k1_gemm(
    const float* __restrict__ X, const unsigned short* __restrict__ Wph,
    const unsigned short* __restrict__ Wpl,
    const float* __restrict__ biasp, float* __restrict__ xal) {
    __shared__ __align__(16) unsigned short Ah[10240];   // [co][kq] stride 40 (80 B rows)
    __shared__ __align__(16) unsigned short Al[10240];
    __shared__ __align__(16) unsigned short Bh[5120];    // [n][kq] stride 40, n 0..127
    __shared__ __align__(16) unsigned short Bl[5120];

    int t = threadIdx.x;
    int n0 = blockIdx.x * 128;
    int b  = blockIdx.y;
    const float* Xb = X + (size_t)b * NC * HW;

    int lane = t & 63, wv = t >> 6;          // 8 waves
    int lcol = lane & 15, lq = lane >> 4;

    f32x4 acc[2][8];
#pragma unroll
    for (int i = 0; i < 2; i++)
#pragma unroll
        for (int j = 0; j < 8; j++) { f32x4 z = {0.f, 0.f, 0.f, 0.f}; acc[i][j] = z; }

    int bn  = t & 127;        // pixel within tile
    int kq2 = t >> 7;         // 0..3 -> k values kq2*8 .. kq2*8+7

    float pf[8];              // B prefetch registers (static indexing only)

    // ---- prologue: B(0) loads (oldest), then A(0) global_load_lds ----
    {
        const float* src = Xb + (size_t)(kq2 * 8) * HW + n0 + bn;
#pragma unroll
        for (int j = 0; j < 8; j++) pf[j] = src[(size_t)j * HW];
    }
    {
        const char* gah = (const char*)Wph;
        const char* gal = (const char*)Wpl;
#pragma unroll
        for (int i = 0; i < 3; i++) {
            if (i < 2 || wv < 4) {           // wave-uniform guard; covers 20480 B
                int off = i * 8192 + wv * 1024;
                __builtin_amdgcn_global_load_lds(
                    (const __attribute__((address_space(1))) unsigned int*)(gah + off + lane * 16),
                    (__attribute__((address_space(3))) unsigned int*)((char*)Ah + off),
                    16, 0, 0);
                __builtin_amdgcn_global_load_lds(
                    (const __attribute__((address_space(1))) unsigned int*)(gal + off + lane * 16),
                    (__attribute__((address_space(3))) unsigned int*)((char*)Al + off),
                    16, 0, 0);
            }
        }
    }

    for (int kk = 0; kk < 8; kk++) {
        // ---- convert prefetched B(kk) -> LDS (single b128 hi + b128 lo per thread) ----
        {
            unsigned hi[4], lo[4];
#pragma unroll
            for (int j = 0; j < 4; j++) {
                unsigned short a = f2bf(pf[2 * j]);
                unsigned short c = f2bf(pf[2 * j + 1]);
                hi[j] = (unsigned)a | ((unsigned)c << 16);
                unsigned short la = f2bf(pf[2 * j] - bf2f(a));
                unsigned short lc = f2bf(pf[2 * j + 1] - bf2f(c));
                lo[j] = (unsigned)la | ((unsigned)lc << 16);
            }
            *(uint4*)(&Bh[bn * 40 + kq2 * 8]) = make_uint4(hi[0], hi[1], hi[2], hi[3]);
            *(uint4*)(&Bl[bn * 40 + kq2 * 8]) = make_uint4(lo[0], lo[1], lo[2], lo[3]);
        }
        __syncthreads();   // drains A(kk) gload_lds + B ds_writes

        short8 afh[2], afl[2];
#pragma unroll
        for (int mt = 0; mt < 2; mt++) {
            afh[mt] = *(const short8*)(&Ah[(wv * 32 + mt * 16 + lcol) * 40 + lq * 8]);
            afl[mt] = *(const short8*)(&Al[(wv * 32 + mt * 16 + lcol) * 40 + lq * 8]);
        }
        // ---- prefetch B(kk+1); latency hides under the MFMA phase ----
        if (kk < 7) {
            const float* src = Xb + (size_t)((kk + 1) * 32 + kq2 * 8) * HW + n0 + bn;
#pragma unroll
            for (int j = 0; j < 8; j++) pf[j] = src[(size_t)j * HW];
        }
#pragma unroll
        for (int nt = 0; nt < 8; nt++) {
            short8 bh = *(const short8*)(&Bh[(nt * 16 + lcol) * 40 + lq * 8]);
            short8 bl = *(const short8*)(&Bl[(nt * 16 + lcol) * 40 + lq * 8]);
#pragma unroll
            for (int mt = 0; mt < 2; mt++) {
                acc[mt][nt] = __builtin_amdgcn_mfma_f32_16x16x32_bf16(
                    afh[mt], bh, acc[mt][nt], 0, 0, 0);
                acc[mt][nt] = __builtin_amdgcn_mfma_f32_16x16x32_bf16(
                    afh[mt], bl, acc[mt][nt], 0, 0, 0);
                acc[mt][nt] = __builtin_amdgcn_mfma_f32_16x16x32_bf16(
                    afl[mt], bh, acc[mt][nt], 0, 0, 0);
            }
        }
        // raw barrier: all waves' ds_reads are consumed by MFMAs issued above, so LDS
        // reuse is safe; does NOT drain the in-flight B prefetch / A gload_lds.
        asm volatile("s_barrier" ::: "memory");
        if (kk < 7) {
            const char* gah = (const char*)(Wph + (kk + 1) * 10240);
            const char* gal = (const char*)(Wpl + (kk + 1) * 10240);
#pragma unroll
            for (int i = 0; i < 3; i++) {
                if (i < 2 || wv < 4) {
                    int off = i * 8192 + wv * 1024;
                    __builtin_amdgcn_global_load_lds(
                        (const __attribute__((address_space(1))) unsigned int*)(gah + off + lane * 16),
                        (__attribute__((address_space(3))) unsigned int*)((char*)Ah + off),
                        16, 0, 0);
                    __builtin_amdgcn_global_load_lds(
                        (const __attribute__((address_space(1))) unsigned int*)(gal + off + lane * 16),
                        (__attribute__((address_space(3))) unsigned int*)((char*)Al + off),
                        16, 0, 0);
                }
            }
        }
    }
#pragma unroll
    for (int mt = 0; mt < 2; mt++) {
#pragma unroll
        for (int r = 0; r < 4; r++) {
            int co = wv * 32 + mt * 16 + lq * 4 + r;
            float bias = biasp[co];
            size_t rowbase = ((size_t)b * NC + co) * HW + n0;
#pragma unroll
            for (int nt = 0; nt < 8; nt++) {
                int n = nt * 16 + lcol;
                float y = acc[mt][nt][r] + bias;
                float z = y / (1.f + __expf(-y));   // SiLU
                xal[rowbase + n] = z;
            }
        }
    }
}

// ---------------- KA: per-(b,c) stats, float4 banded version ----------------
// Block = (b,c,band of 40 rows), 320 threads. 320 ≡ 0 (mod 40) => each thread's
// cell-column (t%40)/10 is INVARIANT across iterations: no predication at all.
__global__ void ka_stats(const float* __restrict__ xal,
                         float* __restrict__ cellsum, float* __restrict__ cellmax) {
    __shared__ float rs[320], rm[320];
    int blk = blockIdx.x;                 // 8192 = 2048 bc * 4 bands
    int bc = blk >> 2, band = blk & 3;
    const float* base = xal + (size_t)bc * HW + band * 6400;
    int t = threadIdx.x;                  // 0..319
    int col = (t % 40) / 10;              // fixed cell column for this thread
    float s = 0.f, m = -3.4e38f;
#pragma unroll
    for (int i = 0; i < 5; i++) {
        f32x4 v = *(const f32x4*)(base + (size_t)(i * 320 + t) * 4);
        s += (v[0] + v[1]) + (v[2] + v[3]);
        m = fmaxf(fmaxf(fmaxf(m, v[0]), fmaxf(v[1], v[2])), v[3]);
    }
    int slot = (t / 40) * 10 + (t % 10);  // 0..79, bijective within col
    rs[col * 80 + slot] = s;
    rm[col * 80 + slot] = m;
    __syncthreads();
    if (t < 64) {
#pragma unroll
        for (int c2 = 0; c2 < 4; c2++) {
            float sv = rs[c2 * 80 + t] + ((t < 16) ? rs[c2 * 80 + 64 + t] : 0.f);
            float mv = fmaxf(rm[c2 * 80 + t],
                             (t < 16) ? rm[c2 * 80 + 64 + t] : -3.4e38f);
#pragma unroll
            for (int off = 32; off >= 1; off >>= 1) {
                sv += __shfl_down(sv, off, 64);
                mv = fmaxf(mv, __shfl_down(mv, off, 64));
            }
            if (t == 0) {
                cellsum[bc * 16 + band * 4 + c2] = sv;
                cellmax[bc * 16 + band * 4 + c2] = mv;
            }
        }
    }
}

// ---------------- KB: channel attention -> ca ----------------
__global__ void kb_attn(const float* __restrict__ cellsum, const float* __restrict__ cellmax,
                        const float* __restrict__ mw1, const float* __restrict__ mw2,
                        const float* __restrict__ lw1, const float* __restrict__ lw2,
                        const float* __restrict__ fw, float* __restrict__ ca) {
    __shared__ float avgS[256], maxS[256], locS[256 * 16], hid[32], hlS[256];
    int b = blockIdx.x, t = threadIdx.x;
    float s = 0.f, m = -3.4e38f;
#pragma unroll
    for (int cell = 0; cell < 16; cell++) {
        float cs = cellsum[(b * 256 + t) * 16 + cell];
        float cm = cellmax[(b * 256 + t) * 16 + cell];
        s += cs;
        m = fmaxf(m, cm);
        locS[t * 16 + cell] = cs * (1.f / 1600.f);
    }
    avgS[t] = s * (1.f / 25600.f);
    maxS[t] = m;
    __syncthreads();
    if (t < 32) {
        int j = t & 15;
        const float* w1 = mw1 + j * 256;
        const float* src = (t < 16) ? avgS : maxS;
        float h = 0.f;
        for (int c = 0; c < 256; c++) h += w1[c] * src[c];
        hid[t] = fmaxf(h, 0.f);
    }
    {
        int cell = t >> 4, j = t & 15;
        const float* w1 = lw1 + j * 256;
        float h = 0.f;
        for (int c = 0; c < 256; c++) h += w1[c] * locS[c * 16 + cell];
        hlS[t] = fmaxf(h, 0.f);       // hlS[cell*16 + j]
    }
    __syncthreads();
    float ga = 0.f, gm = 0.f;
#pragma unroll
    for (int j = 0; j < 16; j++) {
        float w2 = mw2[t * 16 + j];
        ga += w2 * hid[j];
        gm += w2 * hid[16 + j];
    }
    float la = 0.f;
#pragma unroll
    for (int cell = 0; cell < 16; cell++)
#pragma unroll
        for (int j = 0; j < 16; j++)
            la += lw2[t * 16 + j] * hlS[cell * 16 + j];
    float alpha = 1.f / (1.f + expf(-fw[0]));
    float pre = alpha * (ga + gm) + (1.f - alpha) * (la * (1.f / 16.f));
    ca[b * 256 + t] = 1.f / (1.f + expf(-pre));
}

// ---------------- K3: sf = channel avg/max of ca*x ----------------
__global__ void k3_sf(const float* __restrict__ xal,
                      const float* __restrict__ ca, float* __restrict__ sf) {
    __shared__ float cas[256];
    int b = blockIdx.y, t = threadIdx.x;
    cas[t] = ca[b * 256 + t];
    __syncthreads();
    int p = blockIdx.x * 256 + t;      // one pixel per thread
    const float* base = xal + (size_t)b * NC * HW + p;
    float s0 = 0.f, m0 = -3.4e38f;
    for (int c = 0; c < 256; c++) {
        float a0 = cas[c] * base[(size_t)c * HW];
        s0 += a0;
        m0 = fmaxf(m0, a0);
    }
    sf[(size_t)b * 2 * HW + p]      = s0 * (1.f / 256.f);
    sf[(size_t)b * 2 * HW + HW + p] = m0;
}

// ---------------- K4: offset conv1 3x3 + inline BN + ReLU ----------------
__global__ void k4_conv1(const float* __restrict__ sf, const float* __restrict__ ow1,
                         const float* __restrict__ og, const float* __restrict__ obt,
                         const float* __restrict__ om, const float* __restrict__ ov,
                         float* __restrict__ o1) {
    __shared__ float wS[288], scS[16], shS[16];
    int b = blockIdx.y, t = threadIdx.x;
    for (int i = t; i < 288; i += 256) wS[i] = ow1[i];
    if (t < 16) {
        float sc = og[t] * rsqrtf(ov[t] + 1e-5f);
        scS[t] = sc;
        shS[t] = obt[t] - om[t] * sc;
    }
    __syncthreads();
    int p = blockIdx.x * 256 + t;
    int h = p / 160, w = p - h * 160;
    const float* a0 = sf + (size_t)b * 2 * HW;
    const float* a1 = a0 + HW;
    float in0[9], in1[9];
#pragma unroll
    for (int kh = 0; kh < 3; kh++)
#pragma unroll
        for (int kw = 0; kw < 3; kw++) {
            int hh = h + kh - 1, ww = w + kw - 1;
            bool ok = (hh >= 0) & (hh < 160) & (ww >= 0) & (ww < 160);
            int q = hh * 160 + ww;
            in0[kh * 3 + kw] = ok ? a0[q] : 0.f;
            in1[kh * 3 + kw] = ok ? a1[q] : 0.f;
        }
    float* outb = o1 + (size_t)b * 16 * HW + p;
#pragma unroll
    for (int j = 0; j < 16; j++) {
        float acc = 0.f;
#pragma unroll
        for (int k = 0; k < 9; k++)
            acc += wS[j * 18 + k] * in0[k] + wS[j * 18 + 9 + k] * in1[k];
        outb[(size_t)j * HW] = fmaxf(acc * scS[j] + shS[j], 0.f);
    }
}

// ---------------- K5: folded conv2 (2 ch) -> tanh -> grid_sample ----------------
__global__ void k5_sample(const float* __restrict__ o1, const float* __restrict__ weff,
                          const float* __restrict__ beff, const float* __restrict__ sf,
                          float* __restrict__ sampled) {
    __shared__ float tileS[16 * 18 * 18];
    __shared__ float wS[288];
    __shared__ float bS[2];
    int b = blockIdx.y, t = threadIdx.x;
    int ty0 = (blockIdx.x / 10) * 16, tx0 = (blockIdx.x % 10) * 16;
    const float* ob = o1 + (size_t)b * 16 * HW;
    for (int i = t; i < 288; i += 256) wS[i] = weff[i];
    if (t < 2) bS[t] = beff[t];
    for (int i = t; i < 16 * 18 * 18; i += 256) {
        int ci = i / 324, rem = i - ci * 324;
        int r = rem / 18, c = rem - r * 18;
        int gr = ty0 + r - 1, gc = tx0 + c - 1;
        bool ok = (gr >= 0) & (gr < 160) & (gc >= 0) & (gc < 160);
        tileS[i] = ok ? ob[(size_t)ci * HW + gr * 160 + gc] : 0.f;
    }
    __syncthreads();
    int ty = t >> 4, tx = t & 15;
    int h = ty0 + ty, w = tx0 + tx;
    int p = h * 160 + w;
    float s0 = bS[0], s1 = bS[1];
#pragma unroll
    for (int ci = 0; ci < 16; ci++) {
        const float* tb = &tileS[ci * 324 + ty * 18 + tx];
        const float* w0 = &wS[ci * 9];
        const float* w1 = &wS[144 + ci * 9];
#pragma unroll
        for (int kh = 0; kh < 3; kh++)
#pragma unroll
            for (int kw = 0; kw < 3; kw++) {
                float v = tb[kh * 18 + kw];
                s0 += w0[kh * 3 + kw] * v;
                s1 += w1[kh * 3 + kw] * v;
            }
    }
    float ox = tanhf(s0) * 0.5f;
    float oy = tanhf(s1) * 0.5f;
    float bx = w * (2.f / 159.f) - 1.f, by = h * (2.f / 159.f) - 1.f;
    float gxn = fminf(fmaxf(bx + ox, -1.f), 1.f);
    float gyn = fminf(fmaxf(by + oy, -1.f), 1.f);
    float gx = (gxn + 1.f) * 80.f - 0.5f;
    float gy = (gyn + 1.f) * 80.f - 0.5f;
    float x0f = floorf(gx), y0f = floorf(gy);
    float wx = gx - x0f, wy = gy - y0f;
    int ix0 = (int)x0f, iy0 = (int)y0f;
    const float* f0 = sf + (size_t)b * 2 * HW;
    const float* f1 = f0 + HW;
    float r0 = 0.f, r1 = 0.f;
#pragma unroll
    for (int dy = 0; dy < 2; dy++)
#pragma unroll
        for (int dx = 0; dx < 2; dx++) {
            int xi = ix0 + dx, yi = iy0 + dy;
            float wgt = (dx ? wx : 1.f - wx) * (dy ? wy : 1.f - wy);
            if ((xi >= 0) & (xi < 160) & (yi >= 0) & (yi < 160)) {
                int q = yi * 160 + xi;
                r0 += wgt * f0[q];
                r1 += wgt * f1[q];
            }
        }
    float* sb = sampled + (size_t)b * 2 * HW + p;
    sb[0] = r0;
    sb[HW] = r1;
}

// ---------------- K5b: 7x7 attn conv + sigmoid -> sa ----------------
__global__ void k5b_sa(const float* __restrict__ sampled, const float* __restrict__ attn_w,
                       float* __restrict__ sa) {
    __shared__ float wS[98];
    int b = blockIdx.y, t = threadIdx.x;
    if (t < 98) wS[t] = attn_w[t];
    __syncthreads();
    int p = blockIdx.x * 256 + t;
    int h = p / 160, w = p - h * 160;
    const float* s0 = sampled + (size_t)b * 2 * HW;
    const float* s1 = s0 + HW;
    float acc = 0.f;
#pragma unroll
    for (int kh = 0; kh < 7; kh++) {
        int hh = h + kh - 3;
        if (hh < 0 || hh >= 160) continue;
#pragma unroll
        for (int kw = 0; kw < 7; kw++) {
            int ww = w + kw - 3;
            if (ww < 0 || ww >= 160) continue;
            int q = hh * 160 + ww;
            acc += wS[kh * 7 + kw] * s0[q] + wS[49 + kh * 7 + kw] * s1[q];
        }
    }
    sa[(size_t)b * HW + p] = 1.f / (1.f + expf(-acc));
}

// ---------------- K6: out = sa * ca * x_al (in place, float4) ----------------
__global__ void k6_out(float* __restrict__ out, const float* __restrict__ ca,
                       const float* __restrict__ sa) {
    unsigned e4 = blockIdx.x * 256 + threadIdx.x;
    unsigned e = e4 * 4;
    unsigned b = e / (256u * HW);
    unsigned rem = e - b * (256u * HW);
    unsigned c = rem / HW;
    unsigned p = rem - c * HW;          // p % 4 == 0 (HW divisible by 4)
    f32x4 v = *(f32x4*)(out + e);
    f32x4 s = *(const f32x4*)(sa + (size_t)b * HW + p);
    float cav = ca[b * 256 + c];
#pragma unroll
    for (int i = 0; i < 4; i++) v[i] = cav * s[i] * v[i];
    *(f32x4*)(out + e) = v;
}

extern "C" void kernel_launch(void* const* d_in, const int* in_sizes, int n_in,
                              void* d_out, int out_size, void* d_ws, size_t ws_size,
                              hipStream_t stream) {
    const float* x       = (const float*)d_in[0];
    const float* align_w = (const float*)d_in[1];
    const float* align_g = (const float*)d_in[2];
    const float* align_b = (const float*)d_in[3];
    const float* align_m = (const float*)d_in[4];
    const float* align_v = (const float*)d_in[5];
    const float* mlp_w1  = (const float*)d_in[6];
    const float* mlp_w2  = (const float*)d_in[7];
    const float* loc_w1  = (const float*)d_in[8];
    const float* loc_w2  = (const float*)d_in[9];
    const float* fusion  = (const float*)d_in[10];
    const float* off_w1  = (const float*)d_in[11];
    const float* off_g   = (const float*)d_in[12];
    const float* off_bt  = (const float*)d_in[13];
    const float* off_m   = (const float*)d_in[14];
    const float* off_v   = (const float*)d_in[15];
    const float* off_w2  = (const float*)d_in[16];
    const float* off_b2  = (const float*)d_in[17];
    const float* attn_w  = (const float*)d_in[18];
    float* out = (float*)d_out;

    char* wsb = (char*)d_ws;
    size_t off = 0;
    auto alloc = [&](size_t bytes) -> void* {
        off = (off + 255) & ~(size_t)255;
        void* p = wsb + off;
        off += bytes;
        return p;
    };
    float* xal = out;   // x_aligned fp32 lives in d_out until K6 rescales in place
    unsigned short* wph = (unsigned short*)alloc(81920 * 2);   // padded per-kk image, hi
    unsigned short* wpl = (unsigned short*)alloc(81920 * 2);   // padded per-kk image, lo
    float* biasp   = (float*)alloc(256 * 4);
    float* cellsum = (float*)alloc(32768 * 4);
    float* cellmax = (float*)alloc(32768 * 4);
    float* ca      = (float*)alloc(2048 * 4);
    float* sf      = (float*)alloc((size_t)NB * 2 * HW * 4);
    float* o1      = (float*)alloc((size_t)NB * 16 * HW * 4);
    float* sampled = (float*)alloc((size_t)NB * 2 * HW * 4);
    float* sa      = (float*)alloc((size_t)NB * HW * 4);
    float* weff    = (float*)alloc(288 * 4);
    float* beff    = (float*)alloc(2 * 4);
    (void)ws_size; (void)in_sizes; (void)n_in; (void)out_size;

    k0_fold<<<dim3(256), 256, 0, stream>>>(align_w, align_g, align_b, align_m, align_v,
                                           wph, wpl, biasp);
    k0b_fold2<<<dim3(1), 320, 0, stream>>>(off_w2, off_b2, weff, beff);
    k1_gemm<<<dim3(200, 8), 512, 0, stream>>>(x, wph, wpl, biasp, xal);
    ka_stats<<<dim3(8192), 320, 0, stream>>>(xal, cellsum, cellmax);
    kb_attn<<<dim3(8), 256, 0, stream>>>(cellsum, cellmax, mlp_w1, mlp_w2,
                                         loc_w1, loc_w2, fusion, ca);
    k3_sf<<<dim3(100, 8), 256, 0, stream>>>(xal, ca, sf);
    k4_conv1<<<dim3(100, 8), 256, 0, stream>>>(sf, off_w1, off_g, off_bt, off_m, off_v, o1);
    k5_sample<<<dim3(100, 8), 256, 0, stream>>>(o1, weff, beff, sf, sampled);
    k5b_sa<<<dim3(100, 8), 256, 0, stream>>>(sampled, attn_w, sa);
    k6_out<<<dim3(51200), 256, 0, stream>>>(out, ca, sa);
}

// Round 7
// 705.967 us; speedup vs baseline: 1.0037x; 1.0037x over previous
//
#include <hip/hip_runtime.h>
#include <hip/hip_bf16.h>

#define HH 160
#define WW 160
#define HW 25600
#define NC 256
#define NB 8

typedef short short8 __attribute__((ext_vector_type(8)));
typedef float f32x4 __attribute__((ext_vector_type(4)));

__device__ __forceinline__ unsigned short f2bf(float f) {
    unsigned u = __float_as_uint(f);
    u += 0x7fffu + ((u >> 16) & 1u);   // RNE
    return (unsigned short)(u >> 16);
}
__device__ __forceinline__ float bf2f(unsigned short h) {
    return __uint_as_float(((unsigned)h) << 16);
}

// ---------------- K0: fold BN into align 1x1 conv, split hi/lo bf16, pre-pack ----------------
// Writes the padded per-kk LDS image directly: wpkh[kk*10240 + co*40 + kq] (kq = k - 32*kk).
__global__ void k0_fold(const float* __restrict__ aw, const float* __restrict__ ag,
                        const float* __restrict__ ab, const float* __restrict__ am,
                        const float* __restrict__ av,
                        unsigned short* __restrict__ wpkh, unsigned short* __restrict__ wpkl,
                        float* __restrict__ biasp) {
    int co = blockIdx.x, t = threadIdx.x;       // t = k (ci)
    float sc = ag[co] * rsqrtf(av[co] + 1e-5f);
    float w = aw[co * 256 + t] * sc;
    unsigned short h = f2bf(w);
    int kk = t >> 5, kq = t & 31;
    wpkh[kk * 10240 + co * 40 + kq] = h;
    wpkl[kk * 10240 + co * 40 + kq] = f2bf(w - bf2f(h));
    if (t == 0) biasp[co] = ab[co] - am[co] * sc;
}

// ---------------- K0b: fold the 49-way mean of conv2 into effective weights ----------------
__global__ void k0b_fold2(const float* __restrict__ ow2, const float* __restrict__ ob2,
                          float* __restrict__ weff, float* __restrict__ beff) {
    int t = threadIdx.x;
    if (t < 288) {
        int g = t / 144, r = t - g * 144;
        float s = 0.f;
        for (int q = 0; q < 49; q++) s += ow2[(size_t)(g * 49 + q) * 144 + r];
        weff[t] = s * (1.f / 49.f);
    }
    if (t < 2) {
        float s = 0.f;
        for (int q = 0; q < 49; q++) s += ob2[t * 49 + q];
        beff[t] = s * (1.f / 49.f);
    }
}

// ---------------- K1: align GEMM (split-bf16 MFMA, ~fp32) + bias + SiLU ----------------
// 512 threads = 8 waves; BM=256 (wave owns 32 co), BN=128, BK=32.
// launch_bounds(512,2): VGPR cap 256 — R6's (512,4) clamped VGPR to 64 and spilled the
// accumulator (FETCH/WRITE grew, 175us). LDS (60KB) caps blocks/CU at 2 anyway, so this
// gives 16 waves/CU (2x R3) WITHOUT spills.
// NOTE: nt loop MUST be fully unrolled (R1 post-mortem: runtime-indexed acc -> scratch).
__global__ __launch_bounds__(512, 2) void k1_gemm(
    const float* __restrict__ X, const unsigned short* __restrict__ Wph,
    const unsigned short* __restrict__ Wpl,
    const float* __restrict__ biasp, float* __restrict__ xal) {
    __shared__ __align__(16) unsigned short Ah[10240];   // [co][kq] stride 40 (80 B rows)
    __shared__ __align__(16) unsigned short Al[10240];
    __shared__ __align__(16) unsigned short Bh[5120];    // [n][kq] stride 40, n 0..127
    __shared__ __align__(16) unsigned short Bl[5120];

    int t = threadIdx.x;
    int n0 = blockIdx.x * 128;
    int b  = blockIdx.y;
    const float* Xb = X + (size_t)b * NC * HW;

    int lane = t & 63, wv = t >> 6;          // 8 waves
    int lcol = lane & 15, lq = lane >> 4;

    f32x4 acc[2][8];
#pragma unroll
    for (int i = 0; i < 2; i++)
#pragma unroll
        for (int j = 0; j < 8; j++) { f32x4 z = {0.f, 0.f, 0.f, 0.f}; acc[i][j] = z; }

    int bn  = t & 127;        // pixel within tile
    int kq2 = t >> 7;         // 0..3 -> k values kq2*8 .. kq2*8+7

    float pf[8];              // B prefetch registers (static indexing only)

    // ---- prologue: B(0) loads (oldest), then A(0) global_load_lds ----
    {
        const float* src = Xb + (size_t)(kq2 * 8) * HW + n0 + bn;
#pragma unroll
        for (int j = 0; j < 8; j++) pf[j] = src[(size_t)j * HW];
    }
    {
        const char* gah = (const char*)Wph;
        const char* gal = (const char*)Wpl;
#pragma unroll
        for (int i = 0; i < 3; i++) {
            if (i < 2 || wv < 4) {           // wave-uniform guard; covers 20480 B
                int off = i * 8192 + wv * 1024;
                __builtin_amdgcn_global_load_lds(
                    (const __attribute__((address_space(1))) unsigned int*)(gah + off + lane * 16),
                    (__attribute__((address_space(3))) unsigned int*)((char*)Ah + off),
                    16, 0, 0);
                __builtin_amdgcn_global_load_lds(
                    (const __attribute__((address_space(1))) unsigned int*)(gal + off + lane * 16),
                    (__attribute__((address_space(3))) unsigned int*)((char*)Al + off),
                    16, 0, 0);
            }
        }
    }

    for (int kk = 0; kk < 8; kk++) {
        // ---- convert prefetched B(kk) -> LDS (single b128 hi + b128 lo per thread) ----
        {
            unsigned hi[4], lo[4];
#pragma unroll
            for (int j = 0; j < 4; j++) {
                unsigned short a = f2bf(pf[2 * j]);
                unsigned short c = f2bf(pf[2 * j + 1]);
                hi[j] = (unsigned)a | ((unsigned)c << 16);
                unsigned short la = f2bf(pf[2 * j] - bf2f(a));
                unsigned short lc = f2bf(pf[2 * j + 1] - bf2f(c));
                lo[j] = (unsigned)la | ((unsigned)lc << 16);
            }
            *(uint4*)(&Bh[bn * 40 + kq2 * 8]) = make_uint4(hi[0], hi[1], hi[2], hi[3]);
            *(uint4*)(&Bl[bn * 40 + kq2 * 8]) = make_uint4(lo[0], lo[1], lo[2], lo[3]);
        }
        __syncthreads();   // drains A(kk) gload_lds + B ds_writes

        short8 afh[2], afl[2];
#pragma unroll
        for (int mt = 0; mt < 2; mt++) {
            afh[mt] = *(const short8*)(&Ah[(wv * 32 + mt * 16 + lcol) * 40 + lq * 8]);
            afl[mt] = *(const short8*)(&Al[(wv * 32 + mt * 16 + lcol) * 40 + lq * 8]);
        }
        // ---- prefetch B(kk+1); latency hides under the MFMA phase ----
        if (kk < 7) {
            const float* src = Xb + (size_t)((kk + 1) * 32 + kq2 * 8) * HW + n0 + bn;
#pragma unroll
            for (int j = 0; j < 8; j++) pf[j] = src[(size_t)j * HW];
        }
#pragma unroll
        for (int nt = 0; nt < 8; nt++) {
            short8 bh = *(const short8*)(&Bh[(nt * 16 + lcol) * 40 + lq * 8]);
            short8 bl = *(const short8*)(&Bl[(nt * 16 + lcol) * 40 + lq * 8]);
#pragma unroll
            for (int mt = 0; mt < 2; mt++) {
                acc[mt][nt] = __builtin_amdgcn_mfma_f32_16x16x32_bf16(
                    afh[mt], bh, acc[mt][nt], 0, 0, 0);
                acc[mt][nt] = __builtin_amdgcn_mfma_f32_16x16x32_bf16(
                    afh[mt], bl, acc[mt][nt], 0, 0, 0);
                acc[mt][nt] = __builtin_amdgcn_mfma_f32_16x16x32_bf16(
                    afl[mt], bh, acc[mt][nt], 0, 0, 0);
            }
        }
        // raw barrier: all waves' ds_reads are consumed by MFMAs issued above, so LDS
        // reuse is safe; does NOT drain the in-flight B prefetch / A gload_lds.
        asm volatile("s_barrier" ::: "memory");
        if (kk < 7) {
            const char* gah = (const char*)(Wph + (kk + 1) * 10240);
            const char* gal = (const char*)(Wpl + (kk + 1) * 10240);
#pragma unroll
            for (int i = 0; i < 3; i++) {
                if (i < 2 || wv < 4) {
                    int off = i * 8192 + wv * 1024;
                    __builtin_amdgcn_global_load_lds(
                        (const __attribute__((address_space(1))) unsigned int*)(gah + off + lane * 16),
                        (__attribute__((address_space(3))) unsigned int*)((char*)Ah + off),
                        16, 0, 0);
                    __builtin_amdgcn_global_load_lds(
                        (const __attribute__((address_space(1))) unsigned int*)(gal + off + lane * 16),
                        (__attribute__((address_space(3))) unsigned int*)((char*)Al + off),
                        16, 0, 0);
                }
            }
        }
    }
#pragma unroll
    for (int mt = 0; mt < 2; mt++) {
#pragma unroll
        for (int r = 0; r < 4; r++) {
            int co = wv * 32 + mt * 16 + lq * 4 + r;
            float bias = biasp[co];
            size_t rowbase = ((size_t)b * NC + co) * HW + n0;
#pragma unroll
            for (int nt = 0; nt < 8; nt++) {
                int n = nt * 16 + lcol;
                float y = acc[mt][nt][r] + bias;
                float z = y / (1.f + __expf(-y));   // SiLU
                xal[rowbase + n] = z;
            }
        }
    }
}

// ---------------- KA: per-(b,c) stats, float4 banded version ----------------
// Block = (b,c,band of 40 rows), 320 threads. 320 ≡ 0 (mod 40) => each thread's
// cell-column (t%40)/10 is INVARIANT across iterations: no predication at all.
__global__ void ka_stats(const float* __restrict__ xal,
                         float* __restrict__ cellsum, float* __restrict__ cellmax) {
    __shared__ float rs[320], rm[320];
    int blk = blockIdx.x;                 // 8192 = 2048 bc * 4 bands
    int bc = blk >> 2, band = blk & 3;
    const float* base = xal + (size_t)bc * HW + band * 6400;
    int t = threadIdx.x;                  // 0..319
    int col = (t % 40) / 10;              // fixed cell column for this thread
    float s = 0.f, m = -3.4e38f;
#pragma unroll
    for (int i = 0; i < 5; i++) {
        f32x4 v = *(const f32x4*)(base + (size_t)(i * 320 + t) * 4);
        s += (v[0] + v[1]) + (v[2] + v[3]);
        m = fmaxf(fmaxf(fmaxf(m, v[0]), fmaxf(v[1], v[2])), v[3]);
    }
    int slot = (t / 40) * 10 + (t % 10);  // 0..79, bijective within col
    rs[col * 80 + slot] = s;
    rm[col * 80 + slot] = m;
    __syncthreads();
    if (t < 64) {
#pragma unroll
        for (int c2 = 0; c2 < 4; c2++) {
            float sv = rs[c2 * 80 + t] + ((t < 16) ? rs[c2 * 80 + 64 + t] : 0.f);
            float mv = fmaxf(rm[c2 * 80 + t],
                             (t < 16) ? rm[c2 * 80 + 64 + t] : -3.4e38f);
#pragma unroll
            for (int off = 32; off >= 1; off >>= 1) {
                sv += __shfl_down(sv, off, 64);
                mv = fmaxf(mv, __shfl_down(mv, off, 64));
            }
            if (t == 0) {
                cellsum[bc * 16 + band * 4 + c2] = sv;
                cellmax[bc * 16 + band * 4 + c2] = mv;
            }
        }
    }
}

// ---------------- KB: channel attention -> ca ----------------
__global__ void kb_attn(const float* __restrict__ cellsum, const float* __restrict__ cellmax,
                        const float* __restrict__ mw1, const float* __restrict__ mw2,
                        const float* __restrict__ lw1, const float* __restrict__ lw2,
                        const float* __restrict__ fw, float* __restrict__ ca) {
    __shared__ float avgS[256], maxS[256], locS[256 * 16], hid[32], hlS[256];
    int b = blockIdx.x, t = threadIdx.x;
    float s = 0.f, m = -3.4e38f;
#pragma unroll
    for (int cell = 0; cell < 16; cell++) {
        float cs = cellsum[(b * 256 + t) * 16 + cell];
        float cm = cellmax[(b * 256 + t) * 16 + cell];
        s += cs;
        m = fmaxf(m, cm);
        locS[t * 16 + cell] = cs * (1.f / 1600.f);
    }
    avgS[t] = s * (1.f / 25600.f);
    maxS[t] = m;
    __syncthreads();
    if (t < 32) {
        int j = t & 15;
        const float* w1 = mw1 + j * 256;
        const float* src = (t < 16) ? avgS : maxS;
        float h = 0.f;
        for (int c = 0; c < 256; c++) h += w1[c] * src[c];
        hid[t] = fmaxf(h, 0.f);
    }
    {
        int cell = t >> 4, j = t & 15;
        const float* w1 = lw1 + j * 256;
        float h = 0.f;
        for (int c = 0; c < 256; c++) h += w1[c] * locS[c * 16 + cell];
        hlS[t] = fmaxf(h, 0.f);       // hlS[cell*16 + j]
    }
    __syncthreads();
    float ga = 0.f, gm = 0.f;
#pragma unroll
    for (int j = 0; j < 16; j++) {
        float w2 = mw2[t * 16 + j];
        ga += w2 * hid[j];
        gm += w2 * hid[16 + j];
    }
    float la = 0.f;
#pragma unroll
    for (int cell = 0; cell < 16; cell++)
#pragma unroll
        for (int j = 0; j < 16; j++)
            la += lw2[t * 16 + j] * hlS[cell * 16 + j];
    float alpha = 1.f / (1.f + expf(-fw[0]));
    float pre = alpha * (ga + gm) + (1.f - alpha) * (la * (1.f / 16.f));
    ca[b * 256 + t] = 1.f / (1.f + expf(-pre));
}

// ---------------- K3: sf = channel avg/max of ca*x ----------------
__global__ void k3_sf(const float* __restrict__ xal,
                      const float* __restrict__ ca, float* __restrict__ sf) {
    __shared__ float cas[256];
    int b = blockIdx.y, t = threadIdx.x;
    cas[t] = ca[b * 256 + t];
    __syncthreads();
    int p = blockIdx.x * 256 + t;      // one pixel per thread
    const float* base = xal + (size_t)b * NC * HW + p;
    float s0 = 0.f, m0 = -3.4e38f;
    for (int c = 0; c < 256; c++) {
        float a0 = cas[c] * base[(size_t)c * HW];
        s0 += a0;
        m0 = fmaxf(m0, a0);
    }
    sf[(size_t)b * 2 * HW + p]      = s0 * (1.f / 256.f);
    sf[(size_t)b * 2 * HW + HW + p] = m0;
}

// ---------------- K45: fused conv1(3x3,BN,ReLU) + conv2(folded,2ch) + tanh + grid_sample ----
// Per 16x16 output tile: stage sf halo [2][20][20], compute o1 tile [16][18][18] in LDS
// (k4's arithmetic, same order), then conv2 + sample. Eliminates the o1 global round-trip.
__global__ void k45_sample(const float* __restrict__ sf, const float* __restrict__ ow1,
                           const float* __restrict__ og, const float* __restrict__ obt,
                           const float* __restrict__ om, const float* __restrict__ ov,
                           const float* __restrict__ weff, const float* __restrict__ beff,
                           float* __restrict__ sampled) {
    __shared__ float sfS[800];          // [2][20][20], rows ty0-2..ty0+17
    __shared__ float tileS[16 * 18 * 18];
    __shared__ float w1S[288], scS[16], shS[16];
    __shared__ float wS[288];
    __shared__ float bS[2];
    int b = blockIdx.y, t = threadIdx.x;
    int ty0 = (blockIdx.x / 10) * 16, tx0 = (blockIdx.x % 10) * 16;
    const float* f0 = sf + (size_t)b * 2 * HW;
    const float* f1 = f0 + HW;
    for (int i = t; i < 288; i += 256) { w1S[i] = ow1[i]; wS[i] = weff[i]; }
    if (t < 16) {
        float sc = og[t] * rsqrtf(ov[t] + 1e-5f);
        scS[t] = sc;
        shS[t] = obt[t] - om[t] * sc;
    }
    if (t < 2) bS[t] = beff[t];
    for (int i = t; i < 800; i += 256) {
        int ch = i / 400, rem = i - ch * 400;
        int r = rem / 20, c = rem - r * 20;
        int gr = ty0 + r - 2, gc = tx0 + c - 2;
        bool ok = (gr >= 0) & (gr < 160) & (gc >= 0) & (gc < 160);
        sfS[i] = ok ? f0[(size_t)ch * HW + gr * 160 + gc] : 0.f;
    }
    __syncthreads();
    // conv1 + BN + ReLU -> o1 tile (zero outside image, matching k4/k5 semantics)
    for (int i = t; i < 16 * 324; i += 256) {
        int ci = i / 324, rem = i - ci * 324;
        int r = rem / 18, c = rem - r * 18;
        int gr = ty0 + r - 1, gc = tx0 + c - 1;
        float acc = 0.f;
#pragma unroll
        for (int kh = 0; kh < 3; kh++)
#pragma unroll
            for (int kw = 0; kw < 3; kw++) {
                int k = kh * 3 + kw;
                acc += w1S[ci * 18 + k]     * sfS[(r + kh) * 20 + (c + kw)]
                     + w1S[ci * 18 + 9 + k] * sfS[400 + (r + kh) * 20 + (c + kw)];
            }
        bool ok = (gr >= 0) & (gr < 160) & (gc >= 0) & (gc < 160);
        tileS[i] = ok ? fmaxf(acc * scS[ci] + shS[ci], 0.f) : 0.f;
    }
    __syncthreads();
    int ty = t >> 4, tx = t & 15;
    int h = ty0 + ty, w = tx0 + tx;
    int p = h * 160 + w;
    float s0 = bS[0], s1 = bS[1];
#pragma unroll
    for (int ci = 0; ci < 16; ci++) {
        const float* tb = &tileS[ci * 324 + ty * 18 + tx];
        const float* w0 = &wS[ci * 9];
        const float* w1 = &wS[144 + ci * 9];
#pragma unroll
        for (int kh = 0; kh < 3; kh++)
#pragma unroll
            for (int kw = 0; kw < 3; kw++) {
                float v = tb[kh * 18 + kw];
                s0 += w0[kh * 3 + kw] * v;
                s1 += w1[kh * 3 + kw] * v;
            }
    }
    float ox = tanhf(s0) * 0.5f;
    float oy = tanhf(s1) * 0.5f;
    float bx = w * (2.f / 159.f) - 1.f, by = h * (2.f / 159.f) - 1.f;
    float gxn = fminf(fmaxf(bx + ox, -1.f), 1.f);
    float gyn = fminf(fmaxf(by + oy, -1.f), 1.f);
    float gx = (gxn + 1.f) * 80.f - 0.5f;
    float gy = (gyn + 1.f) * 80.f - 0.5f;
    float x0f = floorf(gx), y0f = floorf(gy);
    float wx = gx - x0f, wy = gy - y0f;
    int ix0 = (int)x0f, iy0 = (int)y0f;
    float r0 = 0.f, r1 = 0.f;
#pragma unroll
    for (int dy = 0; dy < 2; dy++)
#pragma unroll
        for (int dx = 0; dx < 2; dx++) {
            int xi = ix0 + dx, yi = iy0 + dy;
            float wgt = (dx ? wx : 1.f - wx) * (dy ? wy : 1.f - wy);
            if ((xi >= 0) & (xi < 160) & (yi >= 0) & (yi < 160)) {
                int q = yi * 160 + xi;
                r0 += wgt * f0[q];
                r1 += wgt * f1[q];
            }
        }
    float* sb = sampled + (size_t)b * 2 * HW + p;
    sb[0] = r0;
    sb[HW] = r1;
}

// ---------------- K5b: 7x7 attn conv + sigmoid -> sa ----------------
__global__ void k5b_sa(const float* __restrict__ sampled, const float* __restrict__ attn_w,
                       float* __restrict__ sa) {
    __shared__ float wS[98];
    int b = blockIdx.y, t = threadIdx.x;
    if (t < 98) wS[t] = attn_w[t];
    __syncthreads();
    int p = blockIdx.x * 256 + t;
    int h = p / 160, w = p - h * 160;
    const float* s0 = sampled + (size_t)b * 2 * HW;
    const float* s1 = s0 + HW;
    float acc = 0.f;
#pragma unroll
    for (int kh = 0; kh < 7; kh++) {
        int hh = h + kh - 3;
        if (hh < 0 || hh >= 160) continue;
#pragma unroll
        for (int kw = 0; kw < 7; kw++) {
            int ww = w + kw - 3;
            if (ww < 0 || ww >= 160) continue;
            int q = hh * 160 + ww;
            acc += wS[kh * 7 + kw] * s0[q] + wS[49 + kh * 7 + kw] * s1[q];
        }
    }
    sa[(size_t)b * HW + p] = 1.f / (1.f + expf(-acc));
}

// ---------------- K6: out = sa * ca * x_al (in place, float4) ----------------
__global__ void k6_out(float* __restrict__ out, const float* __restrict__ ca,
                       const float* __restrict__ sa) {
    unsigned e4 = blockIdx.x * 256 + threadIdx.x;
    unsigned e = e4 * 4;
    unsigned b = e / (256u * HW);
    unsigned rem = e - b * (256u * HW);
    unsigned c = rem / HW;
    unsigned p = rem - c * HW;          // p % 4 == 0 (HW divisible by 4)
    f32x4 v = *(f32x4*)(out + e);
    f32x4 s = *(const f32x4*)(sa + (size_t)b * HW + p);
    float cav = ca[b * 256 + c];
#pragma unroll
    for (int i = 0; i < 4; i++) v[i] = cav * s[i] * v[i];
    *(f32x4*)(out + e) = v;
}

extern "C" void kernel_launch(void* const* d_in, const int* in_sizes, int n_in,
                              void* d_out, int out_size, void* d_ws, size_t ws_size,
                              hipStream_t stream) {
    const float* x       = (const float*)d_in[0];
    const float* align_w = (const float*)d_in[1];
    const float* align_g = (const float*)d_in[2];
    const float* align_b = (const float*)d_in[3];
    const float* align_m = (const float*)d_in[4];
    const float* align_v = (const float*)d_in[5];
    const float* mlp_w1  = (const float*)d_in[6];
    const float* mlp_w2  = (const float*)d_in[7];
    const float* loc_w1  = (const float*)d_in[8];
    const float* loc_w2  = (const float*)d_in[9];
    const float* fusion  = (const float*)d_in[10];
    const float* off_w1  = (const float*)d_in[11];
    const float* off_g   = (const float*)d_in[12];
    const float* off_bt  = (const float*)d_in[13];
    const float* off_m   = (const float*)d_in[14];
    const float* off_v   = (const float*)d_in[15];
    const float* off_w2  = (const float*)d_in[16];
    const float* off_b2  = (const float*)d_in[17];
    const float* attn_w  = (const float*)d_in[18];
    float* out = (float*)d_out;

    char* wsb = (char*)d_ws;
    size_t off = 0;
    auto alloc = [&](size_t bytes) -> void* {
        off = (off + 255) & ~(size_t)255;
        void* p = wsb + off;
        off += bytes;
        return p;
    };
    float* xal = out;   // x_aligned fp32 lives in d_out until K6 rescales in place
    unsigned short* wph = (unsigned short*)alloc(81920 * 2);   // padded per-kk image, hi
    unsigned short* wpl = (unsigned short*)alloc(81920 * 2);   // padded per-kk image, lo
    float* biasp   = (float*)alloc(256 * 4);
    float* cellsum = (float*)alloc(32768 * 4);
    float* cellmax = (float*)alloc(32768 * 4);
    float* ca      = (float*)alloc(2048 * 4);
    float* sf      = (float*)alloc((size_t)NB * 2 * HW * 4);
    float* sampled = (float*)alloc((size_t)NB * 2 * HW * 4);
    float* sa      = (float*)alloc((size_t)NB * HW * 4);
    float* weff    = (float*)alloc(288 * 4);
    float* beff    = (float*)alloc(2 * 4);
    (void)ws_size; (void)in_sizes; (void)n_in; (void)out_size;

    k0_fold<<<dim3(256), 256, 0, stream>>>(align_w, align_g, align_b, align_m, align_v,
                                           wph, wpl, biasp);
    k0b_fold2<<<dim3(1), 320, 0, stream>>>(off_w2, off_b2, weff, beff);
    k1_gemm<<<dim3(200, 8), 512, 0, stream>>>(x, wph, wpl, biasp, xal);
    ka_stats<<<dim3(8192), 320, 0, stream>>>(xal, cellsum, cellmax);
    kb_attn<<<dim3(8), 256, 0, stream>>>(cellsum, cellmax, mlp_w1, mlp_w2,
                                         loc_w1, loc_w2, fusion, ca);
    k3_sf<<<dim3(100, 8), 256, 0, stream>>>(xal, ca, sf);
    k45_sample<<<dim3(100, 8), 256, 0, stream>>>(sf, off_w1, off_g, off_bt, off_m, off_v,
                                                 weff, beff, sampled);
    k5b_sa<<<dim3(100, 8), 256, 0, stream>>>(sampled, attn_w, sa);
    k6_out<<<dim3(51200), 256, 0, stream>>>(out, ca, sa);
}

// Round 8
// 668.760 us; speedup vs baseline: 1.0595x; 1.0556x over previous
//
#include <hip/hip_runtime.h>
#include <hip/hip_bf16.h>

#define HH 160
#define WW 160
#define HW 25600
#define NC 256
#define NB 8

typedef short short8 __attribute__((ext_vector_type(8)));
typedef float f32x4 __attribute__((ext_vector_type(4)));

__device__ __forceinline__ unsigned short f2bf(float f) {
    unsigned u = __float_as_uint(f);
    u += 0x7fffu + ((u >> 16) & 1u);   // RNE
    return (unsigned short)(u >> 16);
}
__device__ __forceinline__ float bf2f(unsigned short h) {
    return __uint_as_float(((unsigned)h) << 16);
}

// ---------------- K0: fold BN into align 1x1 conv, split hi/lo bf16, pre-pack ----------------
__global__ void k0_fold(const float* __restrict__ aw, const float* __restrict__ ag,
                        const float* __restrict__ ab, const float* __restrict__ am,
                        const float* __restrict__ av,
                        unsigned short* __restrict__ wpkh, unsigned short* __restrict__ wpkl,
                        float* __restrict__ biasp) {
    int co = blockIdx.x, t = threadIdx.x;       // t = k (ci)
    float sc = ag[co] * rsqrtf(av[co] + 1e-5f);
    float w = aw[co * 256 + t] * sc;
    unsigned short h = f2bf(w);
    int kk = t >> 5, kq = t & 31;
    wpkh[kk * 10240 + co * 40 + kq] = h;
    wpkl[kk * 10240 + co * 40 + kq] = f2bf(w - bf2f(h));
    if (t == 0) biasp[co] = ab[co] - am[co] * sc;
}

// ---------------- K0b: fold the 49-way mean of conv2 into effective weights ----------------
__global__ void k0b_fold2(const float* __restrict__ ow2, const float* __restrict__ ob2,
                          float* __restrict__ weff, float* __restrict__ beff) {
    int t = threadIdx.x;
    if (t < 288) {
        int g = t / 144, r = t - g * 144;
        float s = 0.f;
        for (int q = 0; q < 49; q++) s += ow2[(size_t)(g * 49 + q) * 144 + r];
        weff[t] = s * (1.f / 49.f);
    }
    if (t < 2) {
        float s = 0.f;
        for (int q = 0; q < 49; q++) s += ob2[t * 49 + q];
        beff[t] = s * (1.f / 49.f);
    }
}

// ---------------- K1: align GEMM (split-bf16 MFMA, ~fp32) + bias + SiLU ----------------
// R3-verified shape: 256 threads = 4 waves; BM=256 (wave owns 64 co), BN=128, BK=32.
// (R6/R7 post-mortem: 8-wave variants were 175us — fewer acc tiles/wave, same 2 blocks/CU.)
// NOTE: nt loop MUST be fully unrolled (R1 post-mortem: runtime-indexed acc -> scratch).
__global__ __launch_bounds__(256, 2) void k1_gemm(
    const float* __restrict__ X, const unsigned short* __restrict__ Wph,
    const unsigned short* __restrict__ Wpl,
    const float* __restrict__ biasp, float* __restrict__ xal) {
    __shared__ __align__(16) unsigned short Ah[10240];   // [co][kq] stride 40 (80 B rows)
    __shared__ __align__(16) unsigned short Al[10240];
    __shared__ __align__(16) unsigned short Bh[5120];    // [n][kq] stride 40, n 0..127
    __shared__ __align__(16) unsigned short Bl[5120];

    int t = threadIdx.x;
    int n0 = blockIdx.x * 128;
    int b  = blockIdx.y;
    const float* Xb = X + (size_t)b * NC * HW;

    int lane = t & 63, wv = t >> 6;
    int lcol = lane & 15, lq = lane >> 4;

    f32x4 acc[4][8];
#pragma unroll
    for (int i = 0; i < 4; i++)
#pragma unroll
        for (int j = 0; j < 8; j++) { f32x4 z = {0.f, 0.f, 0.f, 0.f}; acc[i][j] = z; }

    int bn2 = t & 63;       // pixel-pair index (pixels 2*bn2, 2*bn2+1)
    int bkq = t >> 6;       // base k-quad (== wv)

    float2 pf[8];           // B prefetch registers (static indexing only!)

    // ---- prologue: issue B(0) loads first (older), then A(0) gload_lds (newer) ----
#pragma unroll
    for (int j2 = 0; j2 < 2; j2++) {
        int kq = bkq + 4 * j2;
        const float* src = Xb + (size_t)(kq * 4) * HW + n0 + bn2 * 2;
#pragma unroll
        for (int j = 0; j < 2; j++) {
            pf[j2 * 4 + 2 * j]     = *(const float2*)(src + (size_t)(2 * j) * HW);
            pf[j2 * 4 + 2 * j + 1] = *(const float2*)(src + (size_t)(2 * j + 1) * HW);
        }
    }
    {
        const char* gah = (const char*)Wph;
        const char* gal = (const char*)Wpl;
#pragma unroll
        for (int i = 0; i < 5; i++) {
            int off = wv * 1024 + i * 4096;    // wave-uniform byte offset
            __builtin_amdgcn_global_load_lds(
                (const __attribute__((address_space(1))) unsigned int*)(gah + off + lane * 16),
                (__attribute__((address_space(3))) unsigned int*)((char*)Ah + off),
                16, 0, 0);
            __builtin_amdgcn_global_load_lds(
                (const __attribute__((address_space(1))) unsigned int*)(gal + off + lane * 16),
                (__attribute__((address_space(3))) unsigned int*)((char*)Al + off),
                16, 0, 0);
        }
    }

    for (int kk = 0; kk < 8; kk++) {
        // ---- convert prefetched B(kk) -> LDS ----
#pragma unroll
        for (int j2 = 0; j2 < 2; j2++) {
            int kq = bkq + 4 * j2;
            unsigned h0[2], h1[2], l0[2], l1[2];
#pragma unroll
            for (int j = 0; j < 2; j++) {
                float2 v0 = pf[j2 * 4 + 2 * j];
                float2 v1 = pf[j2 * 4 + 2 * j + 1];
                unsigned short a = f2bf(v0.x), bq = f2bf(v1.x);
                unsigned short c = f2bf(v0.y), d = f2bf(v1.y);
                h0[j] = (unsigned)a | ((unsigned)bq << 16);
                h1[j] = (unsigned)c | ((unsigned)d << 16);
                unsigned short la = f2bf(v0.x - bf2f(a)), lb = f2bf(v1.x - bf2f(bq));
                unsigned short lc = f2bf(v0.y - bf2f(c)), ld = f2bf(v1.y - bf2f(d));
                l0[j] = (unsigned)la | ((unsigned)lb << 16);
                l1[j] = (unsigned)lc | ((unsigned)ld << 16);
            }
            *(uint2*)(&Bh[(bn2 * 2) * 40 + kq * 4])     = make_uint2(h0[0], h0[1]);
            *(uint2*)(&Bh[(bn2 * 2 + 1) * 40 + kq * 4]) = make_uint2(h1[0], h1[1]);
            *(uint2*)(&Bl[(bn2 * 2) * 40 + kq * 4])     = make_uint2(l0[0], l0[1]);
            *(uint2*)(&Bl[(bn2 * 2 + 1) * 40 + kq * 4]) = make_uint2(l1[0], l1[1]);
        }
        __syncthreads();   // drains A(kk) gload_lds + B ds_writes

        short8 afh[4], afl[4];
#pragma unroll
        for (int mt = 0; mt < 4; mt++) {
            afh[mt] = *(const short8*)(&Ah[(wv * 64 + mt * 16 + lcol) * 40 + lq * 8]);
            afl[mt] = *(const short8*)(&Al[(wv * 64 + mt * 16 + lcol) * 40 + lq * 8]);
        }
        // ---- prefetch B(kk+1) into registers; latency hides under MFMA phase ----
        if (kk < 7) {
#pragma unroll
            for (int j2 = 0; j2 < 2; j2++) {
                int kq = bkq + 4 * j2;
                const float* src = Xb + (size_t)((kk + 1) * 32 + kq * 4) * HW + n0 + bn2 * 2;
#pragma unroll
                for (int j = 0; j < 2; j++) {
                    pf[j2 * 4 + 2 * j]     = *(const float2*)(src + (size_t)(2 * j) * HW);
                    pf[j2 * 4 + 2 * j + 1] = *(const float2*)(src + (size_t)(2 * j + 1) * HW);
                }
            }
        }
#pragma unroll
        for (int nt = 0; nt < 8; nt++) {
            short8 bh = *(const short8*)(&Bh[(nt * 16 + lcol) * 40 + lq * 8]);
            short8 bl = *(const short8*)(&Bl[(nt * 16 + lcol) * 40 + lq * 8]);
#pragma unroll
            for (int mt = 0; mt < 4; mt++) {
                acc[mt][nt] = __builtin_amdgcn_mfma_f32_16x16x32_bf16(
                    afh[mt], bh, acc[mt][nt], 0, 0, 0);
                acc[mt][nt] = __builtin_amdgcn_mfma_f32_16x16x32_bf16(
                    afh[mt], bl, acc[mt][nt], 0, 0, 0);
                acc[mt][nt] = __builtin_amdgcn_mfma_f32_16x16x32_bf16(
                    afl[mt], bh, acc[mt][nt], 0, 0, 0);
            }
        }
        // raw barrier: all waves have consumed their ds_reads (MFMA operand waits),
        // so LDS reuse is safe; crucially does NOT drain the in-flight B prefetch.
        asm volatile("s_barrier" ::: "memory");
        if (kk < 7) {
            const char* gah = (const char*)(Wph + (kk + 1) * 10240);
            const char* gal = (const char*)(Wpl + (kk + 1) * 10240);
#pragma unroll
            for (int i = 0; i < 5; i++) {
                int off = wv * 1024 + i * 4096;
                __builtin_amdgcn_global_load_lds(
                    (const __attribute__((address_space(1))) unsigned int*)(gah + off + lane * 16),
                    (__attribute__((address_space(3))) unsigned int*)((char*)Ah + off),
                    16, 0, 0);
                __builtin_amdgcn_global_load_lds(
                    (const __attribute__((address_space(1))) unsigned int*)(gal + off + lane * 16),
                    (__attribute__((address_space(3))) unsigned int*)((char*)Al + off),
                    16, 0, 0);
            }
        }
    }
#pragma unroll
    for (int mt = 0; mt < 4; mt++) {
#pragma unroll
        for (int r = 0; r < 4; r++) {
            int co = wv * 64 + mt * 16 + lq * 4 + r;
            float bias = biasp[co];
            size_t rowbase = ((size_t)b * NC + co) * HW + n0;
#pragma unroll
            for (int nt = 0; nt < 8; nt++) {
                int n = nt * 16 + lcol;
                float y = acc[mt][nt][r] + bias;
                float z = y / (1.f + __expf(-y));   // SiLU
                xal[rowbase + n] = z;
            }
        }
    }
}

// ---------------- KA: per-(b,c) stats, float4 banded version ----------------
__global__ void ka_stats(const float* __restrict__ xal,
                         float* __restrict__ cellsum, float* __restrict__ cellmax) {
    __shared__ float rs[320], rm[320];
    int blk = blockIdx.x;                 // 8192 = 2048 bc * 4 bands
    int bc = blk >> 2, band = blk & 3;
    const float* base = xal + (size_t)bc * HW + band * 6400;
    int t = threadIdx.x;                  // 0..319
    int col = (t % 40) / 10;              // fixed cell column for this thread
    float s = 0.f, m = -3.4e38f;
#pragma unroll
    for (int i = 0; i < 5; i++) {
        f32x4 v = *(const f32x4*)(base + (size_t)(i * 320 + t) * 4);
        s += (v[0] + v[1]) + (v[2] + v[3]);
        m = fmaxf(fmaxf(fmaxf(m, v[0]), fmaxf(v[1], v[2])), v[3]);
    }
    int slot = (t / 40) * 10 + (t % 10);  // 0..79, bijective within col
    rs[col * 80 + slot] = s;
    rm[col * 80 + slot] = m;
    __syncthreads();
    if (t < 64) {
#pragma unroll
        for (int c2 = 0; c2 < 4; c2++) {
            float sv = rs[c2 * 80 + t] + ((t < 16) ? rs[c2 * 80 + 64 + t] : 0.f);
            float mv = fmaxf(rm[c2 * 80 + t],
                             (t < 16) ? rm[c2 * 80 + 64 + t] : -3.4e38f);
#pragma unroll
            for (int off = 32; off >= 1; off >>= 1) {
                sv += __shfl_down(sv, off, 64);
                mv = fmaxf(mv, __shfl_down(mv, off, 64));
            }
            if (t == 0) {
                cellsum[bc * 16 + band * 4 + c2] = sv;
                cellmax[bc * 16 + band * 4 + c2] = mv;
            }
        }
    }
}

// ---------------- KB: channel attention -> ca ----------------
__global__ void kb_attn(const float* __restrict__ cellsum, const float* __restrict__ cellmax,
                        const float* __restrict__ mw1, const float* __restrict__ mw2,
                        const float* __restrict__ lw1, const float* __restrict__ lw2,
                        const float* __restrict__ fw, float* __restrict__ ca) {
    __shared__ float avgS[256], maxS[256], locS[256 * 16], hid[32], hlS[256];
    int b = blockIdx.x, t = threadIdx.x;
    float s = 0.f, m = -3.4e38f;
#pragma unroll
    for (int cell = 0; cell < 16; cell++) {
        float cs = cellsum[(b * 256 + t) * 16 + cell];
        float cm = cellmax[(b * 256 + t) * 16 + cell];
        s += cs;
        m = fmaxf(m, cm);
        locS[t * 16 + cell] = cs * (1.f / 1600.f);
    }
    avgS[t] = s * (1.f / 25600.f);
    maxS[t] = m;
    __syncthreads();
    if (t < 32) {
        int j = t & 15;
        const float* w1 = mw1 + j * 256;
        const float* src = (t < 16) ? avgS : maxS;
        float h = 0.f;
        for (int c = 0; c < 256; c++) h += w1[c] * src[c];
        hid[t] = fmaxf(h, 0.f);
    }
    {
        int cell = t >> 4, j = t & 15;
        const float* w1 = lw1 + j * 256;
        float h = 0.f;
        for (int c = 0; c < 256; c++) h += w1[c] * locS[c * 16 + cell];
        hlS[t] = fmaxf(h, 0.f);       // hlS[cell*16 + j]
    }
    __syncthreads();
    float ga = 0.f, gm = 0.f;
#pragma unroll
    for (int j = 0; j < 16; j++) {
        float w2 = mw2[t * 16 + j];
        ga += w2 * hid[j];
        gm += w2 * hid[16 + j];
    }
    float la = 0.f;
#pragma unroll
    for (int cell = 0; cell < 16; cell++)
#pragma unroll
        for (int j = 0; j < 16; j++)
            la += lw2[t * 16 + j] * hlS[cell * 16 + j];
    float alpha = 1.f / (1.f + expf(-fw[0]));
    float pre = alpha * (ga + gm) + (1.f - alpha) * (la * (1.f / 16.f));
    ca[b * 256 + t] = 1.f / (1.f + expf(-pre));
}

// ---------------- K3: sf = channel avg/max of ca*x (float4 per thread) ----------------
__global__ void k3_sf(const float* __restrict__ xal,
                      const float* __restrict__ ca, float* __restrict__ sf) {
    __shared__ float cas[256];
    int b = blockIdx.y, t = threadIdx.x;
    cas[t] = ca[b * 256 + t];
    __syncthreads();
    int p = (blockIdx.x * 256 + t) * 4;      // 4 pixels per thread
    const float* base = xal + (size_t)b * NC * HW + p;
    f32x4 s = {0.f, 0.f, 0.f, 0.f};
    f32x4 m = {-3.4e38f, -3.4e38f, -3.4e38f, -3.4e38f};
    for (int c = 0; c < 256; c++) {
        f32x4 v = *(const f32x4*)(base + (size_t)c * HW);
        float cav = cas[c];
#pragma unroll
        for (int i = 0; i < 4; i++) {
            float a0 = cav * v[i];
            s[i] += a0;
            m[i] = fmaxf(m[i], a0);
        }
    }
#pragma unroll
    for (int i = 0; i < 4; i++) s[i] *= (1.f / 256.f);
    *(f32x4*)(sf + (size_t)b * 2 * HW + p)      = s;
    *(f32x4*)(sf + (size_t)b * 2 * HW + HW + p) = m;
}

// ---------------- K45: fused conv1(3x3,BN,ReLU) + conv2(folded,2ch) + tanh + grid_sample ----
__global__ void k45_sample(const float* __restrict__ sf, const float* __restrict__ ow1,
                           const float* __restrict__ og, const float* __restrict__ obt,
                           const float* __restrict__ om, const float* __restrict__ ov,
                           const float* __restrict__ weff, const float* __restrict__ beff,
                           float* __restrict__ sampled) {
    __shared__ float sfS[800];          // [2][20][20]
    __shared__ float tileS[16 * 18 * 18];
    __shared__ float w1S[288], scS[16], shS[16];
    __shared__ float wS[288];
    __shared__ float bS[2];
    int b = blockIdx.y, t = threadIdx.x;
    int ty0 = (blockIdx.x / 10) * 16, tx0 = (blockIdx.x % 10) * 16;
    const float* f0 = sf + (size_t)b * 2 * HW;
    const float* f1 = f0 + HW;
    for (int i = t; i < 288; i += 256) { w1S[i] = ow1[i]; wS[i] = weff[i]; }
    if (t < 16) {
        float sc = og[t] * rsqrtf(ov[t] + 1e-5f);
        scS[t] = sc;
        shS[t] = obt[t] - om[t] * sc;
    }
    if (t < 2) bS[t] = beff[t];
    for (int i = t; i < 800; i += 256) {
        int ch = i / 400, rem = i - ch * 400;
        int r = rem / 20, c = rem - r * 20;
        int gr = ty0 + r - 2, gc = tx0 + c - 2;
        bool ok = (gr >= 0) & (gr < 160) & (gc >= 0) & (gc < 160);
        sfS[i] = ok ? f0[(size_t)ch * HW + gr * 160 + gc] : 0.f;
    }
    __syncthreads();
    for (int i = t; i < 16 * 324; i += 256) {
        int ci = i / 324, rem = i - ci * 324;
        int r = rem / 18, c = rem - r * 18;
        int gr = ty0 + r - 1, gc = tx0 + c - 1;
        float acc = 0.f;
#pragma unroll
        for (int kh = 0; kh < 3; kh++)
#pragma unroll
            for (int kw = 0; kw < 3; kw++) {
                int k = kh * 3 + kw;
                acc += w1S[ci * 18 + k]     * sfS[(r + kh) * 20 + (c + kw)]
                     + w1S[ci * 18 + 9 + k] * sfS[400 + (r + kh) * 20 + (c + kw)];
            }
        bool ok = (gr >= 0) & (gr < 160) & (gc >= 0) & (gc < 160);
        tileS[i] = ok ? fmaxf(acc * scS[ci] + shS[ci], 0.f) : 0.f;
    }
    __syncthreads();
    int ty = t >> 4, tx = t & 15;
    int h = ty0 + ty, w = tx0 + tx;
    int p = h * 160 + w;
    float s0 = bS[0], s1 = bS[1];
#pragma unroll
    for (int ci = 0; ci < 16; ci++) {
        const float* tb = &tileS[ci * 324 + ty * 18 + tx];
        const float* w0 = &wS[ci * 9];
        const float* w1 = &wS[144 + ci * 9];
#pragma unroll
        for (int kh = 0; kh < 3; kh++)
#pragma unroll
            for (int kw = 0; kw < 3; kw++) {
                float v = tb[kh * 18 + kw];
                s0 += w0[kh * 3 + kw] * v;
                s1 += w1[kh * 3 + kw] * v;
            }
    }
    float ox = tanhf(s0) * 0.5f;
    float oy = tanhf(s1) * 0.5f;
    float bx = w * (2.f / 159.f) - 1.f, by = h * (2.f / 159.f) - 1.f;
    float gxn = fminf(fmaxf(bx + ox, -1.f), 1.f);
    float gyn = fminf(fmaxf(by + oy, -1.f), 1.f);
    float gx = (gxn + 1.f) * 80.f - 0.5f;
    float gy = (gyn + 1.f) * 80.f - 0.5f;
    float x0f = floorf(gx), y0f = floorf(gy);
    float wx = gx - x0f, wy = gy - y0f;
    int ix0 = (int)x0f, iy0 = (int)y0f;
    float r0 = 0.f, r1 = 0.f;
#pragma unroll
    for (int dy = 0; dy < 2; dy++)
#pragma unroll
        for (int dx = 0; dx < 2; dx++) {
            int xi = ix0 + dx, yi = iy0 + dy;
            float wgt = (dx ? wx : 1.f - wx) * (dy ? wy : 1.f - wy);
            if ((xi >= 0) & (xi < 160) & (yi >= 0) & (yi < 160)) {
                int q = yi * 160 + xi;
                r0 += wgt * f0[q];
                r1 += wgt * f1[q];
            }
        }
    float* sb = sampled + (size_t)b * 2 * HW + p;
    sb[0] = r0;
    sb[HW] = r1;
}

// ---------------- K5b: 7x7 attn conv + sigmoid -> sa (LDS-tiled) ----------------
// 16x16 tile + 22x22x2 halo in LDS; out-of-image taps are staged as 0 (w*0 adds exactly 0).
__global__ void k5b_sa(const float* __restrict__ sampled, const float* __restrict__ attn_w,
                       float* __restrict__ sa) {
    __shared__ float s0S[484], s1S[484], wS[98];
    int b = blockIdx.y, t = threadIdx.x;
    int ty0 = (blockIdx.x / 10) * 16, tx0 = (blockIdx.x % 10) * 16;
    if (t < 98) wS[t] = attn_w[t];
    const float* s0 = sampled + (size_t)b * 2 * HW;
    const float* s1 = s0 + HW;
    for (int i = t; i < 484; i += 256) {
        int r = i / 22, c = i - r * 22;
        int gr = ty0 + r - 3, gc = tx0 + c - 3;
        bool ok = (gr >= 0) & (gr < 160) & (gc >= 0) & (gc < 160);
        int q = gr * 160 + gc;
        s0S[i] = ok ? s0[q] : 0.f;
        s1S[i] = ok ? s1[q] : 0.f;
    }
    __syncthreads();
    int ty = t >> 4, tx = t & 15;
    float acc = 0.f;
#pragma unroll
    for (int kh = 0; kh < 7; kh++)
#pragma unroll
        for (int kw = 0; kw < 7; kw++) {
            int q = (ty + kh) * 22 + (tx + kw);
            acc += wS[kh * 7 + kw] * s0S[q] + wS[49 + kh * 7 + kw] * s1S[q];
        }
    sa[(size_t)b * HW + (ty0 + ty) * 160 + tx0 + tx] = 1.f / (1.f + expf(-acc));
}

// ---------------- K6: out = sa * ca * x_al (in place, float4) ----------------
__global__ void k6_out(float* __restrict__ out, const float* __restrict__ ca,
                       const float* __restrict__ sa) {
    unsigned e4 = blockIdx.x * 256 + threadIdx.x;
    unsigned e = e4 * 4;
    unsigned b = e / (256u * HW);
    unsigned rem = e - b * (256u * HW);
    unsigned c = rem / HW;
    unsigned p = rem - c * HW;          // p % 4 == 0 (HW divisible by 4)
    f32x4 v = *(f32x4*)(out + e);
    f32x4 s = *(const f32x4*)(sa + (size_t)b * HW + p);
    float cav = ca[b * 256 + c];
#pragma unroll
    for (int i = 0; i < 4; i++) v[i] = cav * s[i] * v[i];
    *(f32x4*)(out + e) = v;
}

extern "C" void kernel_launch(void* const* d_in, const int* in_sizes, int n_in,
                              void* d_out, int out_size, void* d_ws, size_t ws_size,
                              hipStream_t stream) {
    const float* x       = (const float*)d_in[0];
    const float* align_w = (const float*)d_in[1];
    const float* align_g = (const float*)d_in[2];
    const float* align_b = (const float*)d_in[3];
    const float* align_m = (const float*)d_in[4];
    const float* align_v = (const float*)d_in[5];
    const float* mlp_w1  = (const float*)d_in[6];
    const float* mlp_w2  = (const float*)d_in[7];
    const float* loc_w1  = (const float*)d_in[8];
    const float* loc_w2  = (const float*)d_in[9];
    const float* fusion  = (const float*)d_in[10];
    const float* off_w1  = (const float*)d_in[11];
    const float* off_g   = (const float*)d_in[12];
    const float* off_bt  = (const float*)d_in[13];
    const float* off_m   = (const float*)d_in[14];
    const float* off_v   = (const float*)d_in[15];
    const float* off_w2  = (const float*)d_in[16];
    const float* off_b2  = (const float*)d_in[17];
    const float* attn_w  = (const float*)d_in[18];
    float* out = (float*)d_out;

    char* wsb = (char*)d_ws;
    size_t off = 0;
    auto alloc = [&](size_t bytes) -> void* {
        off = (off + 255) & ~(size_t)255;
        void* p = wsb + off;
        off += bytes;
        return p;
    };
    float* xal = out;   // x_aligned fp32 lives in d_out until K6 rescales in place
    unsigned short* wph = (unsigned short*)alloc(81920 * 2);   // padded per-kk image, hi
    unsigned short* wpl = (unsigned short*)alloc(81920 * 2);   // padded per-kk image, lo
    float* biasp   = (float*)alloc(256 * 4);
    float* cellsum = (float*)alloc(32768 * 4);
    float* cellmax = (float*)alloc(32768 * 4);
    float* ca      = (float*)alloc(2048 * 4);
    float* sf      = (float*)alloc((size_t)NB * 2 * HW * 4);
    float* sampled = (float*)alloc((size_t)NB * 2 * HW * 4);
    float* sa      = (float*)alloc((size_t)NB * HW * 4);
    float* weff    = (float*)alloc(288 * 4);
    float* beff    = (float*)alloc(2 * 4);
    (void)ws_size; (void)in_sizes; (void)n_in; (void)out_size;

    k0_fold<<<dim3(256), 256, 0, stream>>>(align_w, align_g, align_b, align_m, align_v,
                                           wph, wpl, biasp);
    k0b_fold2<<<dim3(1), 320, 0, stream>>>(off_w2, off_b2, weff, beff);
    k1_gemm<<<dim3(200, 8), 256, 0, stream>>>(x, wph, wpl, biasp, xal);
    ka_stats<<<dim3(8192), 320, 0, stream>>>(xal, cellsum, cellmax);
    kb_attn<<<dim3(8), 256, 0, stream>>>(cellsum, cellmax, mlp_w1, mlp_w2,
                                         loc_w1, loc_w2, fusion, ca);
    k3_sf<<<dim3(25, 8), 256, 0, stream>>>(xal, ca, sf);
    k45_sample<<<dim3(100, 8), 256, 0, stream>>>(sf, off_w1, off_g, off_bt, off_m, off_v,
                                                 weff, beff, sampled);
    k5b_sa<<<dim3(100, 8), 256, 0, stream>>>(sampled, attn_w, sa);
    k6_out<<<dim3(51200), 256, 0, stream>>>(out, ca, sa);
}

// Round 9
// 667.830 us; speedup vs baseline: 1.0610x; 1.0014x over previous
//
#include <hip/hip_runtime.h>
#include <hip/hip_bf16.h>

#define HH 160
#define WW 160
#define HW 25600
#define NC 256
#define NB 8

typedef short short8 __attribute__((ext_vector_type(8)));
typedef float f32x4 __attribute__((ext_vector_type(4)));

__device__ __forceinline__ unsigned short f2bf(float f) {
    unsigned u = __float_as_uint(f);
    u += 0x7fffu + ((u >> 16) & 1u);   // RNE
    return (unsigned short)(u >> 16);
}
__device__ __forceinline__ float bf2f(unsigned short h) {
    return __uint_as_float(((unsigned)h) << 16);
}

// ---------------- K0: fold BN into align conv (blocks 0..255) + conv2 49-mean fold (block 256)
__global__ void k0_fold(const float* __restrict__ aw, const float* __restrict__ ag,
                        const float* __restrict__ ab, const float* __restrict__ am,
                        const float* __restrict__ av,
                        const float* __restrict__ ow2, const float* __restrict__ ob2,
                        unsigned short* __restrict__ wpkh, unsigned short* __restrict__ wpkl,
                        float* __restrict__ biasp,
                        float* __restrict__ weff, float* __restrict__ beff) {
    int t = threadIdx.x;
    if (blockIdx.x < 256) {
        int co = blockIdx.x;                    // t = k (ci)
        float sc = ag[co] * rsqrtf(av[co] + 1e-5f);
        float w = aw[co * 256 + t] * sc;
        unsigned short h = f2bf(w);
        int kk = t >> 5, kq = t & 31;
        wpkh[kk * 10240 + co * 40 + kq] = h;
        wpkl[kk * 10240 + co * 40 + kq] = f2bf(w - bf2f(h));
        if (t == 0) biasp[co] = ab[co] - am[co] * sc;
    } else {
        for (int i = t; i < 288; i += 256) {
            int g = i / 144, r = i - g * 144;
            float s = 0.f;
            for (int q = 0; q < 49; q++) s += ow2[(size_t)(g * 49 + q) * 144 + r];
            weff[i] = s * (1.f / 49.f);
        }
        if (t < 2) {
            float s = 0.f;
            for (int q = 0; q < 49; q++) s += ob2[t * 49 + q];
            beff[t] = s * (1.f / 49.f);
        }
    }
}

// ---------------- K1: align GEMM (split-bf16 MFMA, ~fp32) + bias + SiLU ----------------
// R3-verified shape: 256 threads = 4 waves; BM=256 (wave owns 64 co), BN=128, BK=32.
// (R6/R7 post-mortem: 8-wave variants regressed; R8 vs R4 delta was node clock, not code.)
// NOTE: nt loop MUST be fully unrolled (R1 post-mortem: runtime-indexed acc -> scratch).
__global__ __launch_bounds__(256, 2) void k1_gemm(
    const float* __restrict__ X, const unsigned short* __restrict__ Wph,
    const unsigned short* __restrict__ Wpl,
    const float* __restrict__ biasp, float* __restrict__ xal) {
    __shared__ __align__(16) unsigned short Ah[10240];   // [co][kq] stride 40 (80 B rows)
    __shared__ __align__(16) unsigned short Al[10240];
    __shared__ __align__(16) unsigned short Bh[5120];    // [n][kq] stride 40, n 0..127
    __shared__ __align__(16) unsigned short Bl[5120];

    int t = threadIdx.x;
    int n0 = blockIdx.x * 128;
    int b  = blockIdx.y;
    const float* Xb = X + (size_t)b * NC * HW;

    int lane = t & 63, wv = t >> 6;
    int lcol = lane & 15, lq = lane >> 4;

    f32x4 acc[4][8];
#pragma unroll
    for (int i = 0; i < 4; i++)
#pragma unroll
        for (int j = 0; j < 8; j++) { f32x4 z = {0.f, 0.f, 0.f, 0.f}; acc[i][j] = z; }

    int bn2 = t & 63;       // pixel-pair index (pixels 2*bn2, 2*bn2+1)
    int bkq = t >> 6;       // base k-quad (== wv)

    float2 pf[8];           // B prefetch registers (static indexing only!)

    // ---- prologue: issue B(0) loads first (older), then A(0) gload_lds (newer) ----
#pragma unroll
    for (int j2 = 0; j2 < 2; j2++) {
        int kq = bkq + 4 * j2;
        const float* src = Xb + (size_t)(kq * 4) * HW + n0 + bn2 * 2;
#pragma unroll
        for (int j = 0; j < 2; j++) {
            pf[j2 * 4 + 2 * j]     = *(const float2*)(src + (size_t)(2 * j) * HW);
            pf[j2 * 4 + 2 * j + 1] = *(const float2*)(src + (size_t)(2 * j + 1) * HW);
        }
    }
    {
        const char* gah = (const char*)Wph;
        const char* gal = (const char*)Wpl;
#pragma unroll
        for (int i = 0; i < 5; i++) {
            int off = wv * 1024 + i * 4096;    // wave-uniform byte offset
            __builtin_amdgcn_global_load_lds(
                (const __attribute__((address_space(1))) unsigned int*)(gah + off + lane * 16),
                (__attribute__((address_space(3))) unsigned int*)((char*)Ah + off),
                16, 0, 0);
            __builtin_amdgcn_global_load_lds(
                (const __attribute__((address_space(1))) unsigned int*)(gal + off + lane * 16),
                (__attribute__((address_space(3))) unsigned int*)((char*)Al + off),
                16, 0, 0);
        }
    }

    for (int kk = 0; kk < 8; kk++) {
        // ---- convert prefetched B(kk) -> LDS ----
#pragma unroll
        for (int j2 = 0; j2 < 2; j2++) {
            int kq = bkq + 4 * j2;
            unsigned h0[2], h1[2], l0[2], l1[2];
#pragma unroll
            for (int j = 0; j < 2; j++) {
                float2 v0 = pf[j2 * 4 + 2 * j];
                float2 v1 = pf[j2 * 4 + 2 * j + 1];
                unsigned short a = f2bf(v0.x), bq = f2bf(v1.x);
                unsigned short c = f2bf(v0.y), d = f2bf(v1.y);
                h0[j] = (unsigned)a | ((unsigned)bq << 16);
                h1[j] = (unsigned)c | ((unsigned)d << 16);
                unsigned short la = f2bf(v0.x - bf2f(a)), lb = f2bf(v1.x - bf2f(bq));
                unsigned short lc = f2bf(v0.y - bf2f(c)), ld = f2bf(v1.y - bf2f(d));
                l0[j] = (unsigned)la | ((unsigned)lb << 16);
                l1[j] = (unsigned)lc | ((unsigned)ld << 16);
            }
            *(uint2*)(&Bh[(bn2 * 2) * 40 + kq * 4])     = make_uint2(h0[0], h0[1]);
            *(uint2*)(&Bh[(bn2 * 2 + 1) * 40 + kq * 4]) = make_uint2(h1[0], h1[1]);
            *(uint2*)(&Bl[(bn2 * 2) * 40 + kq * 4])     = make_uint2(l0[0], l0[1]);
            *(uint2*)(&Bl[(bn2 * 2 + 1) * 40 + kq * 4]) = make_uint2(l1[0], l1[1]);
        }
        __syncthreads();   // drains A(kk) gload_lds + B ds_writes

        short8 afh[4], afl[4];
#pragma unroll
        for (int mt = 0; mt < 4; mt++) {
            afh[mt] = *(const short8*)(&Ah[(wv * 64 + mt * 16 + lcol) * 40 + lq * 8]);
            afl[mt] = *(const short8*)(&Al[(wv * 64 + mt * 16 + lcol) * 40 + lq * 8]);
        }
        // ---- prefetch B(kk+1) into registers; latency hides under MFMA phase ----
        if (kk < 7) {
#pragma unroll
            for (int j2 = 0; j2 < 2; j2++) {
                int kq = bkq + 4 * j2;
                const float* src = Xb + (size_t)((kk + 1) * 32 + kq * 4) * HW + n0 + bn2 * 2;
#pragma unroll
                for (int j = 0; j < 2; j++) {
                    pf[j2 * 4 + 2 * j]     = *(const float2*)(src + (size_t)(2 * j) * HW);
                    pf[j2 * 4 + 2 * j + 1] = *(const float2*)(src + (size_t)(2 * j + 1) * HW);
                }
            }
        }
#pragma unroll
        for (int nt = 0; nt < 8; nt++) {
            short8 bh = *(const short8*)(&Bh[(nt * 16 + lcol) * 40 + lq * 8]);
            short8 bl = *(const short8*)(&Bl[(nt * 16 + lcol) * 40 + lq * 8]);
#pragma unroll
            for (int mt = 0; mt < 4; mt++) {
                acc[mt][nt] = __builtin_amdgcn_mfma_f32_16x16x32_bf16(
                    afh[mt], bh, acc[mt][nt], 0, 0, 0);
                acc[mt][nt] = __builtin_amdgcn_mfma_f32_16x16x32_bf16(
                    afh[mt], bl, acc[mt][nt], 0, 0, 0);
                acc[mt][nt] = __builtin_amdgcn_mfma_f32_16x16x32_bf16(
                    afl[mt], bh, acc[mt][nt], 0, 0, 0);
            }
        }
        // raw barrier: all waves have consumed their ds_reads (MFMA operand waits),
        // so LDS reuse is safe; crucially does NOT drain the in-flight B prefetch.
        asm volatile("s_barrier" ::: "memory");
        if (kk < 7) {
            const char* gah = (const char*)(Wph + (kk + 1) * 10240);
            const char* gal = (const char*)(Wpl + (kk + 1) * 10240);
#pragma unroll
            for (int i = 0; i < 5; i++) {
                int off = wv * 1024 + i * 4096;
                __builtin_amdgcn_global_load_lds(
                    (const __attribute__((address_space(1))) unsigned int*)(gah + off + lane * 16),
                    (__attribute__((address_space(3))) unsigned int*)((char*)Ah + off),
                    16, 0, 0);
                __builtin_amdgcn_global_load_lds(
                    (const __attribute__((address_space(1))) unsigned int*)(gal + off + lane * 16),
                    (__attribute__((address_space(3))) unsigned int*)((char*)Al + off),
                    16, 0, 0);
            }
        }
    }
#pragma unroll
    for (int mt = 0; mt < 4; mt++) {
#pragma unroll
        for (int r = 0; r < 4; r++) {
            int co = wv * 64 + mt * 16 + lq * 4 + r;
            float bias = biasp[co];
            size_t rowbase = ((size_t)b * NC + co) * HW + n0;
#pragma unroll
            for (int nt = 0; nt < 8; nt++) {
                int n = nt * 16 + lcol;
                float y = acc[mt][nt][r] + bias;
                float z = y / (1.f + __expf(-y));   // SiLU
                xal[rowbase + n] = z;
            }
        }
    }
}

// ---------------- KA: per-(b,c) stats, float4 banded version ----------------
__global__ void ka_stats(const float* __restrict__ xal,
                         float* __restrict__ cellsum, float* __restrict__ cellmax) {
    __shared__ float rs[320], rm[320];
    int blk = blockIdx.x;                 // 8192 = 2048 bc * 4 bands
    int bc = blk >> 2, band = blk & 3;
    const float* base = xal + (size_t)bc * HW + band * 6400;
    int t = threadIdx.x;                  // 0..319
    int col = (t % 40) / 10;              // fixed cell column for this thread
    float s = 0.f, m = -3.4e38f;
#pragma unroll
    for (int i = 0; i < 5; i++) {
        f32x4 v = *(const f32x4*)(base + (size_t)(i * 320 + t) * 4);
        s += (v[0] + v[1]) + (v[2] + v[3]);
        m = fmaxf(fmaxf(fmaxf(m, v[0]), fmaxf(v[1], v[2])), v[3]);
    }
    int slot = (t / 40) * 10 + (t % 10);  // 0..79, bijective within col
    rs[col * 80 + slot] = s;
    rm[col * 80 + slot] = m;
    __syncthreads();
    if (t < 64) {
#pragma unroll
        for (int c2 = 0; c2 < 4; c2++) {
            float sv = rs[c2 * 80 + t] + ((t < 16) ? rs[c2 * 80 + 64 + t] : 0.f);
            float mv = fmaxf(rm[c2 * 80 + t],
                             (t < 16) ? rm[c2 * 80 + 64 + t] : -3.4e38f);
#pragma unroll
            for (int off = 32; off >= 1; off >>= 1) {
                sv += __shfl_down(sv, off, 64);
                mv = fmaxf(mv, __shfl_down(mv, off, 64));
            }
            if (t == 0) {
                cellsum[bc * 16 + band * 4 + c2] = sv;
                cellmax[bc * 16 + band * 4 + c2] = mv;
            }
        }
    }
}

// ---------------- KB: channel attention -> ca ----------------
__global__ void kb_attn(const float* __restrict__ cellsum, const float* __restrict__ cellmax,
                        const float* __restrict__ mw1, const float* __restrict__ mw2,
                        const float* __restrict__ lw1, const float* __restrict__ lw2,
                        const float* __restrict__ fw, float* __restrict__ ca) {
    __shared__ float avgS[256], maxS[256], locS[256 * 16], hid[32], hlS[256];
    int b = blockIdx.x, t = threadIdx.x;
    float s = 0.f, m = -3.4e38f;
#pragma unroll
    for (int cell = 0; cell < 16; cell++) {
        float cs = cellsum[(b * 256 + t) * 16 + cell];
        float cm = cellmax[(b * 256 + t) * 16 + cell];
        s += cs;
        m = fmaxf(m, cm);
        locS[t * 16 + cell] = cs * (1.f / 1600.f);
    }
    avgS[t] = s * (1.f / 25600.f);
    maxS[t] = m;
    __syncthreads();
    if (t < 32) {
        int j = t & 15;
        const float* w1 = mw1 + j * 256;
        const float* src = (t < 16) ? avgS : maxS;
        float h = 0.f;
        for (int c = 0; c < 256; c++) h += w1[c] * src[c];
        hid[t] = fmaxf(h, 0.f);
    }
    {
        int cell = t >> 4, j = t & 15;
        const float* w1 = lw1 + j * 256;
        float h = 0.f;
        for (int c = 0; c < 256; c++) h += w1[c] * locS[c * 16 + cell];
        hlS[t] = fmaxf(h, 0.f);       // hlS[cell*16 + j]
    }
    __syncthreads();
    float ga = 0.f, gm = 0.f;
#pragma unroll
    for (int j = 0; j < 16; j++) {
        float w2 = mw2[t * 16 + j];
        ga += w2 * hid[j];
        gm += w2 * hid[16 + j];
    }
    float la = 0.f;
#pragma unroll
    for (int cell = 0; cell < 16; cell++)
#pragma unroll
        for (int j = 0; j < 16; j++)
            la += lw2[t * 16 + j] * hlS[cell * 16 + j];
    float alpha = 1.f / (1.f + expf(-fw[0]));
    float pre = alpha * (ga + gm) + (1.f - alpha) * (la * (1.f / 16.f));
    ca[b * 256 + t] = 1.f / (1.f + expf(-pre));
}

// ---------------- K3: sf = channel avg/max of ca*x (float2, 400 blocks) ----------------
// R8 post-mortem: float4 version had only 200 blocks (<1/CU) — occupancy-starved a 210MB
// stream. float2 x 2px/thread = 400 blocks / 1600 waves, 512B per wave-instr.
__global__ void k3_sf(const float* __restrict__ xal,
                      const float* __restrict__ ca, float* __restrict__ sf) {
    __shared__ float cas[256];
    int b = blockIdx.y, t = threadIdx.x;
    cas[t] = ca[b * 256 + t];
    __syncthreads();
    int p = (blockIdx.x * 256 + t) * 2;      // 2 pixels per thread
    const float* base = xal + (size_t)b * NC * HW + p;
    float s0 = 0.f, s1 = 0.f;
    float m0 = -3.4e38f, m1 = -3.4e38f;
#pragma unroll 8
    for (int c = 0; c < 256; c++) {
        float2 v = *(const float2*)(base + (size_t)c * HW);
        float cav = cas[c];
        float a0 = cav * v.x, a1 = cav * v.y;
        s0 += a0; s1 += a1;
        m0 = fmaxf(m0, a0); m1 = fmaxf(m1, a1);
    }
    float2 sv = make_float2(s0 * (1.f / 256.f), s1 * (1.f / 256.f));
    float2 mv = make_float2(m0, m1);
    *(float2*)(sf + (size_t)b * 2 * HW + p)      = sv;
    *(float2*)(sf + (size_t)b * 2 * HW + HW + p) = mv;
}

// ---------------- K45: fused conv1(3x3,BN,ReLU) + conv2(folded,2ch) + tanh + grid_sample ----
__global__ void k45_sample(const float* __restrict__ sf, const float* __restrict__ ow1,
                           const float* __restrict__ og, const float* __restrict__ obt,
                           const float* __restrict__ om, const float* __restrict__ ov,
                           const float* __restrict__ weff, const float* __restrict__ beff,
                           float* __restrict__ sampled) {
    __shared__ float sfS[800];          // [2][20][20]
    __shared__ float tileS[16 * 18 * 18];
    __shared__ float w1S[288], scS[16], shS[16];
    __shared__ float wS[288];
    __shared__ float bS[2];
    int b = blockIdx.y, t = threadIdx.x;
    int ty0 = (blockIdx.x / 10) * 16, tx0 = (blockIdx.x % 10) * 16;
    const float* f0 = sf + (size_t)b * 2 * HW;
    const float* f1 = f0 + HW;
    for (int i = t; i < 288; i += 256) { w1S[i] = ow1[i]; wS[i] = weff[i]; }
    if (t < 16) {
        float sc = og[t] * rsqrtf(ov[t] + 1e-5f);
        scS[t] = sc;
        shS[t] = obt[t] - om[t] * sc;
    }
    if (t < 2) bS[t] = beff[t];
    for (int i = t; i < 800; i += 256) {
        int ch = i / 400, rem = i - ch * 400;
        int r = rem / 20, c = rem - r * 20;
        int gr = ty0 + r - 2, gc = tx0 + c - 2;
        bool ok = (gr >= 0) & (gr < 160) & (gc >= 0) & (gc < 160);
        sfS[i] = ok ? f0[(size_t)ch * HW + gr * 160 + gc] : 0.f;
    }
    __syncthreads();
    for (int i = t; i < 16 * 324; i += 256) {
        int ci = i / 324, rem = i - ci * 324;
        int r = rem / 18, c = rem - r * 18;
        int gr = ty0 + r - 1, gc = tx0 + c - 1;
        float acc = 0.f;
#pragma unroll
        for (int kh = 0; kh < 3; kh++)
#pragma unroll
            for (int kw = 0; kw < 3; kw++) {
                int k = kh * 3 + kw;
                acc += w1S[ci * 18 + k]     * sfS[(r + kh) * 20 + (c + kw)]
                     + w1S[ci * 18 + 9 + k] * sfS[400 + (r + kh) * 20 + (c + kw)];
            }
        bool ok = (gr >= 0) & (gr < 160) & (gc >= 0) & (gc < 160);
        tileS[i] = ok ? fmaxf(acc * scS[ci] + shS[ci], 0.f) : 0.f;
    }
    __syncthreads();
    int ty = t >> 4, tx = t & 15;
    int h = ty0 + ty, w = tx0 + tx;
    int p = h * 160 + w;
    float s0 = bS[0], s1 = bS[1];
#pragma unroll
    for (int ci = 0; ci < 16; ci++) {
        const float* tb = &tileS[ci * 324 + ty * 18 + tx];
        const float* w0 = &wS[ci * 9];
        const float* w1 = &wS[144 + ci * 9];
#pragma unroll
        for (int kh = 0; kh < 3; kh++)
#pragma unroll
            for (int kw = 0; kw < 3; kw++) {
                float v = tb[kh * 18 + kw];
                s0 += w0[kh * 3 + kw] * v;
                s1 += w1[kh * 3 + kw] * v;
            }
    }
    float ox = tanhf(s0) * 0.5f;
    float oy = tanhf(s1) * 0.5f;
    float bx = w * (2.f / 159.f) - 1.f, by = h * (2.f / 159.f) - 1.f;
    float gxn = fminf(fmaxf(bx + ox, -1.f), 1.f);
    float gyn = fminf(fmaxf(by + oy, -1.f), 1.f);
    float gx = (gxn + 1.f) * 80.f - 0.5f;
    float gy = (gyn + 1.f) * 80.f - 0.5f;
    float x0f = floorf(gx), y0f = floorf(gy);
    float wx = gx - x0f, wy = gy - y0f;
    int ix0 = (int)x0f, iy0 = (int)y0f;
    float r0 = 0.f, r1 = 0.f;
#pragma unroll
    for (int dy = 0; dy < 2; dy++)
#pragma unroll
        for (int dx = 0; dx < 2; dx++) {
            int xi = ix0 + dx, yi = iy0 + dy;
            float wgt = (dx ? wx : 1.f - wx) * (dy ? wy : 1.f - wy);
            if ((xi >= 0) & (xi < 160) & (yi >= 0) & (yi < 160)) {
                int q = yi * 160 + xi;
                r0 += wgt * f0[q];
                r1 += wgt * f1[q];
            }
        }
    float* sb = sampled + (size_t)b * 2 * HW + p;
    sb[0] = r0;
    sb[HW] = r1;
}

// ---------------- K5b: 7x7 attn conv + sigmoid -> sa (LDS-tiled) ----------------
__global__ void k5b_sa(const float* __restrict__ sampled, const float* __restrict__ attn_w,
                       float* __restrict__ sa) {
    __shared__ float s0S[484], s1S[484], wS[98];
    int b = blockIdx.y, t = threadIdx.x;
    int ty0 = (blockIdx.x / 10) * 16, tx0 = (blockIdx.x % 10) * 16;
    if (t < 98) wS[t] = attn_w[t];
    const float* s0 = sampled + (size_t)b * 2 * HW;
    const float* s1 = s0 + HW;
    for (int i = t; i < 484; i += 256) {
        int r = i / 22, c = i - r * 22;
        int gr = ty0 + r - 3, gc = tx0 + c - 3;
        bool ok = (gr >= 0) & (gr < 160) & (gc >= 0) & (gc < 160);
        int q = gr * 160 + gc;
        s0S[i] = ok ? s0[q] : 0.f;
        s1S[i] = ok ? s1[q] : 0.f;
    }
    __syncthreads();
    int ty = t >> 4, tx = t & 15;
    float acc = 0.f;
#pragma unroll
    for (int kh = 0; kh < 7; kh++)
#pragma unroll
        for (int kw = 0; kw < 7; kw++) {
            int q = (ty + kh) * 22 + (tx + kw);
            acc += wS[kh * 7 + kw] * s0S[q] + wS[49 + kh * 7 + kw] * s1S[q];
        }
    sa[(size_t)b * HW + (ty0 + ty) * 160 + tx0 + tx] = 1.f / (1.f + expf(-acc));
}

// ---------------- K6: out = sa * ca * x_al (in place, float4) ----------------
__global__ void k6_out(float* __restrict__ out, const float* __restrict__ ca,
                       const float* __restrict__ sa) {
    unsigned e4 = blockIdx.x * 256 + threadIdx.x;
    unsigned e = e4 * 4;
    unsigned b = e / (256u * HW);
    unsigned rem = e - b * (256u * HW);
    unsigned c = rem / HW;
    unsigned p = rem - c * HW;          // p % 4 == 0 (HW divisible by 4)
    f32x4 v = *(f32x4*)(out + e);
    f32x4 s = *(const f32x4*)(sa + (size_t)b * HW + p);
    float cav = ca[b * 256 + c];
#pragma unroll
    for (int i = 0; i < 4; i++) v[i] = cav * s[i] * v[i];
    *(f32x4*)(out + e) = v;
}

extern "C" void kernel_launch(void* const* d_in, const int* in_sizes, int n_in,
                              void* d_out, int out_size, void* d_ws, size_t ws_size,
                              hipStream_t stream) {
    const float* x       = (const float*)d_in[0];
    const float* align_w = (const float*)d_in[1];
    const float* align_g = (const float*)d_in[2];
    const float* align_b = (const float*)d_in[3];
    const float* align_m = (const float*)d_in[4];
    const float* align_v = (const float*)d_in[5];
    const float* mlp_w1  = (const float*)d_in[6];
    const float* mlp_w2  = (const float*)d_in[7];
    const float* loc_w1  = (const float*)d_in[8];
    const float* loc_w2  = (const float*)d_in[9];
    const float* fusion  = (const float*)d_in[10];
    const float* off_w1  = (const float*)d_in[11];
    const float* off_g   = (const float*)d_in[12];
    const float* off_bt  = (const float*)d_in[13];
    const float* off_m   = (const float*)d_in[14];
    const float* off_v   = (const float*)d_in[15];
    const float* off_w2  = (const float*)d_in[16];
    const float* off_b2  = (const float*)d_in[17];
    const float* attn_w  = (const float*)d_in[18];
    float* out = (float*)d_out;

    char* wsb = (char*)d_ws;
    size_t off = 0;
    auto alloc = [&](size_t bytes) -> void* {
        off = (off + 255) & ~(size_t)255;
        void* p = wsb + off;
        off += bytes;
        return p;
    };
    float* xal = out;   // x_aligned fp32 lives in d_out until K6 rescales in place
    unsigned short* wph = (unsigned short*)alloc(81920 * 2);   // padded per-kk image, hi
    unsigned short* wpl = (unsigned short*)alloc(81920 * 2);   // padded per-kk image, lo
    float* biasp   = (float*)alloc(256 * 4);
    float* cellsum = (float*)alloc(32768 * 4);
    float* cellmax = (float*)alloc(32768 * 4);
    float* ca      = (float*)alloc(2048 * 4);
    float* sf      = (float*)alloc((size_t)NB * 2 * HW * 4);
    float* sampled = (float*)alloc((size_t)NB * 2 * HW * 4);
    float* sa      = (float*)alloc((size_t)NB * HW * 4);
    float* weff    = (float*)alloc(288 * 4);
    float* beff    = (float*)alloc(2 * 4);
    (void)ws_size; (void)in_sizes; (void)n_in; (void)out_size;

    k0_fold<<<dim3(257), 256, 0, stream>>>(align_w, align_g, align_b, align_m, align_v,
                                           off_w2, off_b2, wph, wpl, biasp, weff, beff);
    k1_gemm<<<dim3(200, 8), 256, 0, stream>>>(x, wph, wpl, biasp, xal);
    ka_stats<<<dim3(8192), 320, 0, stream>>>(xal, cellsum, cellmax);
    kb_attn<<<dim3(8), 256, 0, stream>>>(cellsum, cellmax, mlp_w1, mlp_w2,
                                         loc_w1, loc_w2, fusion, ca);
    k3_sf<<<dim3(50, 8), 256, 0, stream>>>(xal, ca, sf);
    k45_sample<<<dim3(100, 8), 256, 0, stream>>>(sf, off_w1, off_g, off_bt, off_m, off_v,
                                                 weff, beff, sampled);
    k5b_sa<<<dim3(100, 8), 256, 0, stream>>>(sampled, attn_w, sa);
    k6_out<<<dim3(51200), 256, 0, stream>>>(out, ca, sa);
}